// Round 9
// baseline (23344.348 us; speedup 1.0000x reference)
//
#include <hip/hip_runtime.h>
#include <hip/hip_bf16.h>
#include <math.h>
#include <stdint.h>

typedef long long ll;

__device__ __forceinline__ ll clampi(ll i, ll n) { return i < 0 ? 0 : (i >= n ? n - 1 : i); }

// ---------------- threefry2x32 (20 rounds, JAX/Random123 exact) ----------------
__host__ __device__ inline uint32_t rotl32(uint32_t v, int d) { return (v << d) | (v >> (32 - d)); }

#define TF_R4(a, b, c, d)                              \
  x0 += x1; x1 = rotl32(x1, a); x1 ^= x0;              \
  x0 += x1; x1 = rotl32(x1, b); x1 ^= x0;              \
  x0 += x1; x1 = rotl32(x1, c); x1 ^= x0;              \
  x0 += x1; x1 = rotl32(x1, d); x1 ^= x0;

__host__ __device__ inline void threefry(uint32_t k0, uint32_t k1, uint32_t x0, uint32_t x1,
                                         uint32_t* o0, uint32_t* o1) {
  uint32_t ks2 = k0 ^ k1 ^ 0x1BD11BDAu;
  x0 += k0; x1 += k1;
  TF_R4(13, 15, 26, 6)
  x0 += k1; x1 += ks2 + 1u;
  TF_R4(17, 29, 16, 24)
  x0 += ks2; x1 += k0 + 2u;
  TF_R4(13, 15, 26, 6)
  x0 += k0; x1 += k1 + 3u;
  TF_R4(17, 29, 16, 24)
  x0 += k1; x1 += ks2 + 4u;
  TF_R4(13, 15, 26, 6)
  x0 += ks2; x1 += k0 + 5u;
  *o0 = x0; *o1 = x1;
}

// PE matching np make_pe fp32 pipeline
__device__ __forceinline__ float pe_val(int pos, int d) {
  int k2 = (d >> 1) << 1;
  float div = expf((float)k2 * (-9.210340371976184f / 512.0f));
  float arg = (float)pos * div;
  return (d & 1) ? cosf(arg) : sinf(arg);
}

// ---------------- kernels ----------------

// embed one batch b: out[l,d] = src[b,l,:6]@in_w[:,d] + in_b[d] + pe(l,d)
__global__ __launch_bounds__(256) void embed_b_kernel(const float* __restrict__ src, ll nSrc,
                                                      const float* __restrict__ in_w,
                                                      const float* __restrict__ in_b,
                                                      int b, float* __restrict__ out, ll nOut) {
  ll i = (ll)blockIdx.x * 256 + threadIdx.x;
  if (i >= (ll)2048 * 512) return;
  int d = (int)(i & 511);
  int l = (int)(i >> 9);
  float acc = in_b[clampi(d, 512)];
#pragma unroll
  for (int j = 0; j < 6; j++)
    acc = fmaf(src[clampi(((ll)b * 2048 + l) * 6 + j, nSrc)], in_w[clampi(j * 512 + d, 3072)], acc);
  acc += pe_val(l, d);
  out[clampi(i, nOut)] = acc;
}

// GEMM: C[m,n] = sum_k A[(bcalc*L + l2)*K + k] * W[wOff + k*wSK + n*wSN] (+bias)
// rows global = mBase + m; bcalc = gRow/L, l = gRow%L; shiftMode: 0 none, 1 zero-pad, 2 wrap.
__global__ __launch_bounds__(256) void gemm_kernel(
    const float* __restrict__ A, ll nA,
    int mBase, int L, int K,
    const float* __restrict__ W, ll nW, ll wOff, int wSK, int wSN,
    const float* __restrict__ bias, ll nBias,
    float* __restrict__ C, ll nC, int N,
    int shift, int shiftMode, int accum) {
  __shared__ float As[16][65];
  __shared__ float Bs[16][64];
  const int tid = threadIdx.x;
  const int tx = tid & 15, ty = tid >> 4;
  const int m0 = blockIdx.x * 64, n0 = blockIdx.y * 64;

  const int rowA = tid >> 2;
  const int kA0 = (tid & 3) << 2;
  int gRowG = mBase + m0 + rowA;
  int b = gRowG / L, l = gRowG - b * L;
  int l2 = l;
  bool valid = true;
  if (shiftMode == 1) {
    l2 = l + shift;
    valid = (l2 >= 0 && l2 < L);
    if (!valid) l2 = 0;
  } else if (shiftMode == 2) {
    l2 = l + shift;
    if (l2 < 0) l2 += L; else if (l2 >= L) l2 -= L;
  }
  const ll aRow = (ll)(b * L + l2) * (ll)K;

  const int kB = tid >> 4;
  const int nB0 = (tid & 15) << 2;

  float acc[4][4] = {};

  for (int k0 = 0; k0 < K; k0 += 16) {
#pragma unroll
    for (int jj = 0; jj < 4; jj++) {
      int k = k0 + kA0 + jj;
      As[kA0 + jj][rowA] = valid ? A[clampi(aRow + k, nA)] : 0.f;
    }
    int kw = k0 + kB;
#pragma unroll
    for (int j = 0; j < 4; j++)
      Bs[kB][nB0 + j] = W[clampi(wOff + (ll)kw * wSK + (ll)(n0 + nB0 + j) * wSN, nW)];
    __syncthreads();
#pragma unroll
    for (int kk = 0; kk < 16; kk++) {
      float a0 = As[kk][(ty << 2) + 0], a1 = As[kk][(ty << 2) + 1];
      float a2 = As[kk][(ty << 2) + 2], a3 = As[kk][(ty << 2) + 3];
      float w0 = Bs[kk][(tx << 2) + 0], w1 = Bs[kk][(tx << 2) + 1];
      float w2 = Bs[kk][(tx << 2) + 2], w3 = Bs[kk][(tx << 2) + 3];
      acc[0][0] = fmaf(a0, w0, acc[0][0]); acc[0][1] = fmaf(a0, w1, acc[0][1]);
      acc[0][2] = fmaf(a0, w2, acc[0][2]); acc[0][3] = fmaf(a0, w3, acc[0][3]);
      acc[1][0] = fmaf(a1, w0, acc[1][0]); acc[1][1] = fmaf(a1, w1, acc[1][1]);
      acc[1][2] = fmaf(a1, w2, acc[1][2]); acc[1][3] = fmaf(a1, w3, acc[1][3]);
      acc[2][0] = fmaf(a2, w0, acc[2][0]); acc[2][1] = fmaf(a2, w1, acc[2][1]);
      acc[2][2] = fmaf(a2, w2, acc[2][2]); acc[2][3] = fmaf(a2, w3, acc[2][3]);
      acc[3][0] = fmaf(a3, w0, acc[3][0]); acc[3][1] = fmaf(a3, w1, acc[3][1]);
      acc[3][2] = fmaf(a3, w2, acc[3][2]); acc[3][3] = fmaf(a3, w3, acc[3][3]);
    }
    __syncthreads();
  }
#pragma unroll
  for (int i2 = 0; i2 < 4; i2++) {
    int m = m0 + (ty << 2) + i2;
#pragma unroll
    for (int j = 0; j < 4; j++) {
      int n = n0 + (tx << 2) + j;
      float v = acc[i2][j];
      if (bias) v += bias[clampi(n, nBias)];
      ll off = clampi((ll)m * N + n, nC);
      if (accum) C[off] += v; else C[off] = v;
    }
  }
}

// JAX randint (pow2 span), PARTITIONABLE threefry mode (jax_threefry_partitionable=True,
// default in modern JAX): lower_bits = random_bits(k2, 32, (L,U)) where
//   bits[m] = o0(k2; hi(m), lo(m)) ^ o1(k2; hi(m), lo(m)), 64-bit iota counter (hi=0 here)
__global__ void idx_kernel(int* __restrict__ idx, ll nIdx, uint32_t k0, uint32_t k1, int n,
                           int mask) {
  int m = blockIdx.x * 256 + threadIdx.x;
  if (m < n) {
    uint32_t o0, o1;
    threefry(k0, k1, 0u, (uint32_t)m, &o0, &o1);
    idx[clampi(m, nIdx)] = (int)((o0 ^ o1) & (uint32_t)mask);
  }
}

// M[b,l] = max_u(q.k_samp) - sum_u(q.k_samp)/L for (8, L, 64) per-head tensors
__global__ __launch_bounds__(256) void m_kernel(const float* __restrict__ Q,
                                                const float* __restrict__ Kk, ll nQK,
                                                const int* __restrict__ idx, ll nIdx,
                                                float* __restrict__ M, ll nM, int L, int U) {
  int wid = (int)(((ll)blockIdx.x * 256 + threadIdx.x) >> 6);
  int lane = threadIdx.x & 63;
  if (wid >= 8 * L) return;
  int b = wid / L, l = wid - b * L;
  float qv = Q[clampi((ll)(b * L + l) * 64 + lane, nQK)];
  float mx = -INFINITY, sm = 0.f;
  for (int uu = 0; uu < U; uu++) {
    int kr = idx[clampi((ll)l * U + uu, nIdx)];
    float p = qv * Kk[clampi((ll)(b * L + kr) * 64 + lane, nQK)];
#pragma unroll
    for (int d = 32; d > 0; d >>= 1) p += __shfl_xor(p, d);
    mx = fmaxf(mx, p);
    sm += p;
  }
  if (lane == 0) M[clampi((ll)b * L + l, nM)] = mx - sm / (float)L;
}

// iterative top-u; ties -> smaller index (lax.top_k). Destroys M.
__global__ __launch_bounds__(256) void topk_kernel(float* __restrict__ M, ll nM,
                                                   int* __restrict__ topi, ll nTopi,
                                                   int L, int u) {
  __shared__ float sv[256];
  __shared__ int si[256];
  int t = threadIdx.x;
  ll base = (ll)blockIdx.x * L;
  for (int j = 0; j < u; j++) {
    float bv = -INFINITY; int bi = 0x7fffffff;
    for (int l = t; l < L; l += 256) {
      float v = M[clampi(base + l, nM)];
      if (v > bv) { bv = v; bi = l; }
    }
    sv[t] = bv; si[t] = bi;
    __syncthreads();
    for (int s = 128; s > 0; s >>= 1) {
      if (t < s) {
        float v2 = sv[t + s]; int i2 = si[t + s];
        if (v2 > sv[t] || (v2 == sv[t] && i2 < si[t])) { sv[t] = v2; si[t] = i2; }
      }
      __syncthreads();
    }
    if (t == 0) {
      topi[clampi((ll)blockIdx.x * u + j, nTopi)] = si[0];
      M[clampi(base + si[0], nM)] = -INFINITY;
    }
    __syncthreads();
  }
}

__global__ __launch_bounds__(64) void qgather_kernel(const float* __restrict__ Q, ll nQ,
                                                     const int* __restrict__ topi, ll nTopi,
                                                     float* __restrict__ QR, ll nQR,
                                                     int L, int u) {
  int g = blockIdx.x;
  int b = g / u;
  int row = topi[clampi((ll)g, nTopi)];
  QR[clampi((ll)g * 64 + threadIdx.x, nQR)] =
      Q[clampi((ll)(b * L + row) * 64 + threadIdx.x, nQ)];
}

// vm[b*64+e] = mean_l V[b,l,e]
__global__ __launch_bounds__(256) void vmean_kernel(const float* __restrict__ V, ll nV,
                                                    float* __restrict__ vm, ll nVm, int L) {
  int b = blockIdx.x;
  int e = threadIdx.x & 63, p = threadIdx.x >> 6;
  __shared__ float s[4][64];
  float acc = 0.f;
  for (int l = p; l < L; l += 4) acc += V[clampi((ll)(b * L + l) * 64 + e, nV)];
  s[p][e] = acc;
  __syncthreads();
  if (threadIdx.x < 64)
    vm[clampi((ll)b * 64 + threadIdx.x, nVm)] =
        (s[0][threadIdx.x] + s[1][threadIdx.x] + s[2][threadIdx.x] + s[3][threadIdx.x]) / (float)L;
}

// full attention for one selected query row; write compact upd row (no scatter)
__global__ __launch_bounds__(256) void attn_kernel(const float* __restrict__ QR, ll nQR,
                                                   const float* __restrict__ Kk, ll nK,
                                                   const float* __restrict__ V, ll nV,
                                                   const int* __restrict__ topi, ll nTopi,
                                                   float* __restrict__ upd, ll nUpd,
                                                   int L, int u) {
  int b = blockIdx.x / u;
  __shared__ float qs[64];
  __shared__ float sc[2048];
  __shared__ float red[256];
  __shared__ float upds[4][64];
  int t = threadIdx.x;
  if (t < 64) qs[t] = QR[clampi((ll)blockIdx.x * 64 + t, nQR)];
  __syncthreads();
  float lmax = -INFINITY;
  for (int l = t; l < L; l += 256) {
    ll kb = (ll)(b * L + l) * 64;
    float d = 0.f;
#pragma unroll
    for (int e = 0; e < 64; e++) d = fmaf(qs[e], Kk[clampi(kb + e, nK)], d);
    d *= 0.125f;
    sc[l] = d;
    lmax = fmaxf(lmax, d);
  }
  red[t] = lmax;
  __syncthreads();
  for (int s = 128; s > 0; s >>= 1) { if (t < s) red[t] = fmaxf(red[t], red[t + s]); __syncthreads(); }
  float mx = red[0];
  __syncthreads();
  float lsum = 0.f;
  for (int l = t; l < L; l += 256) { float e = expf(sc[l] - mx); sc[l] = e; lsum += e; }
  red[t] = lsum;
  __syncthreads();
  for (int s = 128; s > 0; s >>= 1) { if (t < s) red[t] += red[t + s]; __syncthreads(); }
  float inv = 1.f / red[0];
  int e = t & 63, p = t >> 6;
  float partial = 0.f;
  for (int l = p; l < L; l += 4)
    partial = fmaf(sc[l], V[clampi((ll)(b * L + l) * 64 + e, nV)], partial);
  upds[p][e] = partial;
  __syncthreads();
  if (t < 64) {
    float s = (upds[0][t] + upds[1][t] + upds[2][t] + upds[3][t]) * inv;
    upd[clampi((ll)blockIdx.x * 64 + t, nUpd)] = s;
  }
}

// BR[b,t] = bo[t] + sum_{h,e} VM[(h*8+b)*64+e] * Wo[wOff + (h*64+e)*512 + t]
__global__ __launch_bounds__(512) void baserow_kernel(const float* __restrict__ VM, ll nVM,
                                                      const float* __restrict__ Wo, ll nWo,
                                                      ll wOff, const float* __restrict__ bo,
                                                      ll nBo, float* __restrict__ BR, ll nBR) {
  int b = blockIdx.x, t = threadIdx.x;
  float acc = bo[clampi(t, nBo)];
  for (int h = 0; h < 8; h++)
#pragma unroll 4
    for (int e = 0; e < 64; e++)
      acc = fmaf(VM[clampi((ll)(h * 8 + b) * 64 + e, nVM)],
                 Wo[clampi(wOff + (ll)(h * 64 + e) * 512 + t, nWo)], acc);
  BR[clampi((ll)b * 512 + t, nBR)] = acc;
}

// X[i] += BR[b(i)*512 + d]
__global__ __launch_bounds__(256) void bcast_kernel(float* __restrict__ X, ll nX,
                                                    const float* __restrict__ BR, ll nBR,
                                                    int L, ll n) {
  ll i = (ll)blockIdx.x * 256 + threadIdx.x;
  if (i >= n) return;
  int d = (int)(i & 511);
  int b = (int)((i >> 9) / L);
  X[clampi(i, nX)] += BR[clampi((ll)b * 512 + d, nBR)];
}

// X[b, topi] += (upd - vm) @ Wo_h ; one block per (h,b,j), atomicAdd (row may be picked by >1 head)
__global__ __launch_bounds__(512) void corr_kernel(const float* __restrict__ UPD, ll nUPD,
                                                   const float* __restrict__ VM, ll nVM,
                                                   const int* __restrict__ topi, ll nTopi,
                                                   const float* __restrict__ Wo, ll nWo, ll wOff,
                                                   float* __restrict__ X, ll nX, int L, int u) {
  int g = blockIdx.x;                 // h*8*u + b*u + j
  int h = g / (8 * u);
  int r = g - h * 8 * u;
  int b = r / u;
  int row = topi[clampi((ll)g, nTopi)];
  int t = threadIdx.x;
  float c = 0.f;
#pragma unroll 4
  for (int e = 0; e < 64; e++) {
    float dv = UPD[clampi((ll)g * 64 + e, nUPD)] - VM[clampi((ll)(h * 8 + b) * 64 + e, nVM)];
    c = fmaf(dv, Wo[clampi(wOff + (ll)(h * 64 + e) * 512 + t, nWo)], c);
  }
  atomicAdd(&X[clampi(((ll)b * L + row) * 512 + t, nX)], c);
}

// layernorm over 512 of (x [+res]); fp32 out (in-place safe per-row)
__global__ __launch_bounds__(256) void ln_kernel(const float* __restrict__ x, ll nX,
                                                 const float* __restrict__ res,
                                                 const float* __restrict__ g,
                                                 const float* __restrict__ be,
                                                 float* __restrict__ out, ll nOut) {
  ll base = (ll)blockIdx.x * 512;
  int t = threadIdx.x;
  float v0 = x[clampi(base + t, nX)], v1 = x[clampi(base + 256 + t, nX)];
  if (res) { v0 += res[clampi(base + t, nX)]; v1 += res[clampi(base + 256 + t, nX)]; }
  __shared__ float red[256];
  red[t] = v0 + v1;
  __syncthreads();
  for (int s = 128; s > 0; s >>= 1) { if (t < s) red[t] += red[t + s]; __syncthreads(); }
  float mu = red[0] * (1.f / 512.f);
  __syncthreads();
  float d0 = v0 - mu, d1 = v1 - mu;
  red[t] = d0 * d0 + d1 * d1;
  __syncthreads();
  for (int s = 128; s > 0; s >>= 1) { if (t < s) red[t] += red[t + s]; __syncthreads(); }
  float rstd = 1.f / sqrtf(red[0] * (1.f / 512.f) + 1e-5f);
  out[clampi(base + t, nOut)] = d0 * rstd * g[clampi(t, 512)] + be[clampi(t, 512)];
  out[clampi(base + 256 + t, nOut)] =
      d1 * rstd * g[clampi(t + 256, 512)] + be[clampi(t + 256, 512)];
}

__global__ __launch_bounds__(256) void gelu_kernel(float* __restrict__ x, ll nX, ll n) {
  ll i = (ll)blockIdx.x * 256 + threadIdx.x;
  if (i >= n) return;
  float v = x[clampi(i, nX)];
  x[clampi(i, nX)] = 0.5f * v * (1.f + erff(v * 0.70710678118654752f));
}

__global__ __launch_bounds__(256) void bnelu_kernel(float* __restrict__ x, ll nX,
                                                    const float* __restrict__ g,
                                                    const float* __restrict__ b,
                                                    const float* __restrict__ rm,
                                                    const float* __restrict__ rv, ll n) {
  ll i = (ll)blockIdx.x * 256 + threadIdx.x;
  if (i >= n) return;
  int c = (int)(i & 511);
  float y = (x[clampi(i, nX)] - rm[clampi(c, 512)]) / sqrtf(rv[clampi(c, 512)] + 1e-5f) *
                g[clampi(c, 512)] +
            b[clampi(c, 512)];
  x[clampi(i, nX)] = y > 0.f ? y : expm1f(y);
}

// maxpool over one batch: in y (L x 512), out (L2 x 512)
__global__ __launch_bounds__(256) void maxpool_kernel(const float* __restrict__ y, ll nY,
                                                      float* __restrict__ outp, ll nOut,
                                                      int L, int L2, ll n) {
  ll i = (ll)blockIdx.x * 256 + threadIdx.x;
  if (i >= n) return;
  int c = (int)(i & 511);
  int l2 = (int)(i >> 9);
  int l0 = 2 * l2 - 1;
  float m = -INFINITY;
#pragma unroll
  for (int w = 0; w < 3; w++) {
    int l = l0 + w;
    if (l >= 0 && l < L) m = fmaxf(m, y[clampi((ll)l * 512 + c, nY)]);
  }
  outp[clampi(i, nOut)] = m;
}

// pred rows t=5..9: tgt = dec_b + pe(t) + pe(b); fp32 out
__global__ __launch_bounds__(64) void pred_kernel(const float* __restrict__ dec_b,
                                                  const float* __restrict__ head_w,
                                                  const float* __restrict__ head_b,
                                                  float* __restrict__ out, ll nOut) {
  int b = blockIdx.x / 5, tt = blockIdx.x % 5, t = 5 + tt;
  int lane = threadIdx.x;
  float a0 = 0.f, a1 = 0.f;
  for (int d = lane; d < 512; d += 64) {
    float td = dec_b[clampi(d, 512)] + pe_val(t, d) + pe_val(b, d);
    a0 = fmaf(td, head_w[clampi(2 * d, 1024)], a0);
    a1 = fmaf(td, head_w[clampi(2 * d + 1, 1024)], a1);
  }
#pragma unroll
  for (int s = 32; s > 0; s >>= 1) { a0 += __shfl_xor(a0, s); a1 += __shfl_xor(a1, s); }
  if (lane == 0) {
    out[clampi((ll)b * 10 + tt * 2 + 0, nOut)] = a0 + head_b[0];
    out[clampi((ll)b * 10 + tt * 2 + 1, nOut)] = a1 + head_b[1];
  }
}

// ---------------- host ----------------
extern "C" void kernel_launch(void* const* d_in, const int* in_sizes, int n_in,
                              void* d_out, int out_size, void* d_ws, size_t ws_size,
                              hipStream_t stream) {
  if (n_in < 34) return;
  if (in_sizes[0] != 8 * 2048 * 6) return;
  if (in_sizes[4] != 512 * 512 * 3) return;
  if (in_sizes[6] != 4 * 512 * 512) return;
  if (in_sizes[22] != 3 * 512 * 512 * 3) return;
  if (in_sizes[33] != 2) return;
  if (ws_size < 55700000) return;   // all-fp32 layout needs ~55.7 MB

  const ll BIG = (ll)8 * 2048 * 512;
  const ll HSZ = (ll)8 * 2048 * 64;   // per-head q/k/v
  const ll CSZ = (ll)2048 * 512;      // chunk scratch

  const float* src    = (const float*)d_in[0];
  const float* in_w   = (const float*)d_in[2];
  const float* in_b   = (const float*)d_in[3];
  const float* conv_w = (const float*)d_in[4];
  const float* conv_b = (const float*)d_in[5];
  const float* wq = (const float*)d_in[6];
  const float* bq = (const float*)d_in[7];
  const float* wk = (const float*)d_in[8];
  const float* bk = (const float*)d_in[9];
  const float* wv = (const float*)d_in[10];
  const float* bv = (const float*)d_in[11];
  const float* wo = (const float*)d_in[12];
  const float* bo = (const float*)d_in[13];
  const float* n1_g = (const float*)d_in[14];
  const float* n1_b = (const float*)d_in[15];
  const float* ff1_w = (const float*)d_in[16];
  const float* ff1_b = (const float*)d_in[17];
  const float* ff2_w = (const float*)d_in[18];
  const float* ff2_b = (const float*)d_in[19];
  const float* n2_g = (const float*)d_in[20];
  const float* n2_b = (const float*)d_in[21];
  const float* dconv_w = (const float*)d_in[22];
  const float* dconv_b = (const float*)d_in[23];
  const float* bn_g = (const float*)d_in[24];
  const float* bn_b = (const float*)d_in[25];
  const float* bn_m = (const float*)d_in[26];
  const float* bn_v = (const float*)d_in[27];
  const float* enc_g = (const float*)d_in[28];
  const float* enc_b = (const float*)d_in[29];
  const float* dec_bv = (const float*)d_in[31];
  const float* head_w = (const float*)d_in[32];
  const float* head_b = (const float*)d_in[33];
  float* out = (float*)d_out;
  const ll nOut = (ll)out_size;

  char* p = (char*)d_ws;
  float* X  = (float*)p; p += BIG * 4;
  float* QH = (float*)p; p += HSZ * 4;
  float* KH = (float*)p; p += HSZ * 4;
  float* VH = (float*)p; p += HSZ * 4;
  float* SC1 = (float*)p; p += CSZ * 4;
  float* SC2 = (float*)p; p += CSZ * 4;
  float* UPD = (float*)p; p += (ll)8 * 8 * 40 * 64 * 4;
  float* VM  = (float*)p; p += (ll)8 * 8 * 64 * 4;
  float* BR  = (float*)p; p += (ll)8 * 512 * 4;
  float* Mh  = (float*)p; p += (ll)8 * 2048 * 4;
  float* QR  = (float*)p; p += (ll)8 * 40 * 64 * 4;
  int* IDX   = (int*)p; p += (ll)2048 * 40 * 4;
  int* TOPIA = (int*)p;

  const ll nIDX = (ll)2048 * 40, nMh = (ll)8 * 2048, nQR = (ll)8 * 40 * 64;
  const ll nUPD = (ll)8 * 8 * 40 * 64, nVM = (ll)8 * 8 * 64, nBR = (ll)8 * 512;
  const ll nTOPIA = (ll)8 * 8 * 40;
  const ll nSrc = (ll)8 * 2048 * 6, nW1 = (ll)4 * 512 * 512;
  const ll nConvW = (ll)512 * 512 * 3, nDconvW = (ll)3 * 512 * 512 * 3;

  // PRNG (JAX PARTITIONABLE threefry mode, modern default):
  //   key_i = fold_in(key(42), i) = threefry((0,42), [0, i])  (mode-independent)
  //   k1,k2 = split(key_i) fold-like: k_j = threefry(key_i, (0, j)); k2 = j=1
  //   randint (pow2 span) uses only lower_bits = random_bits(k2):
  //     bits[m] = o0(k2; 0, m) ^ o1(k2; 0, m)
  uint32_t keys[4][2];
  for (int i = 0; i < 4; i++) {
    uint32_t K0, K1, g0, g1;
    threefry(0u, 42u, 0u, (uint32_t)i, &K0, &K1);   // fold_in
    threefry(K0, K1, 0u, 1u, &g0, &g1);             // split (fold-like), subkey k2
    keys[i][0] = g0;
    keys[i][1] = g1;
  }

  // embed + input conv (zero-pad, 3 taps), per batch through SC1
  for (int b = 0; b < 8; b++) {
    embed_b_kernel<<<(int)((CSZ + 255) / 256), 256, 0, stream>>>(src, nSrc, in_w, in_b, b,
                                                                 SC1, CSZ);
    for (int tp = 0; tp < 3; tp++) {
      gemm_kernel<<<dim3(32, 8), 256, 0, stream>>>(
          SC1, CSZ, 0, 2048, 512, conv_w, nConvW, (ll)tp, 3, 1536,
          (tp == 0 ? conv_b : (const float*)nullptr), 512,
          X + (ll)b * CSZ, BIG - (ll)b * CSZ, 512, tp - 1, 1, (tp > 0) ? 1 : 0);
    }
  }

  const int Ls[4] = {2048, 1024, 512, 256};
  const int Us[4] = {40, 35, 35, 30};

  for (int i = 0; i < 4; i++) {
    int L = Ls[i], U = Us[i];
    int Mrows = 8 * L;
    ll nelem = (ll)Mrows * 512;
    int LU = L * U;
    ll wOff = (ll)i * 262144;

    idx_kernel<<<(LU + 255) / 256, 256, 0, stream>>>(IDX, nIDX, keys[i][0], keys[i][1],
                                                     LU, L - 1);

    for (int h = 0; h < 8; h++) {
      gemm_kernel<<<dim3(Mrows / 64, 1), 256, 0, stream>>>(
          X, BIG, 0, L, 512, wq, nW1, wOff + h * 64, 512, 1,
          bq + i * 512 + h * 64, 64, QH, HSZ, 64, 0, 0, 0);
      gemm_kernel<<<dim3(Mrows / 64, 1), 256, 0, stream>>>(
          X, BIG, 0, L, 512, wk, nW1, wOff + h * 64, 512, 1,
          bk + i * 512 + h * 64, 64, KH, HSZ, 64, 0, 0, 0);
      gemm_kernel<<<dim3(Mrows / 64, 1), 256, 0, stream>>>(
          X, BIG, 0, L, 512, wv, nW1, wOff + h * 64, 512, 1,
          bv + i * 512 + h * 64, 64, VH, HSZ, 64, 0, 0, 0);

      m_kernel<<<(8 * L * 64) / 256, 256, 0, stream>>>(QH, KH, HSZ, IDX, nIDX, Mh, nMh, L, U);
      topk_kernel<<<8, 256, 0, stream>>>(Mh, nMh, TOPIA + (ll)h * 8 * U, nTOPIA - (ll)h * 8 * U,
                                         L, U);
      qgather_kernel<<<8 * U, 64, 0, stream>>>(QH, HSZ, TOPIA + (ll)h * 8 * U,
                                               nTOPIA - (ll)h * 8 * U, QR, nQR, L, U);
      vmean_kernel<<<8, 256, 0, stream>>>(VH, HSZ, VM + (ll)h * 8 * 64,
                                          nVM - (ll)h * 8 * 64, L);
      attn_kernel<<<8 * U, 256, 0, stream>>>(QR, nQR, KH, HSZ, VH, HSZ,
                                             TOPIA + (ll)h * 8 * U, nTOPIA - (ll)h * 8 * U,
                                             UPD + (ll)h * 8 * U * 64,
                                             nUPD - (ll)h * 8 * U * 64, L, U);
    }

    // a = ctx@Wo + bo folded into X: base rows + sparse corrections
    baserow_kernel<<<8, 512, 0, stream>>>(VM, nVM, wo, nW1, wOff, bo + i * 512, 512, BR, nBR);
    bcast_kernel<<<(int)((nelem + 255) / 256), 256, 0, stream>>>(X, BIG, BR, nBR, L, nelem);
    corr_kernel<<<64 * U, 512, 0, stream>>>(UPD, nUPD, VM, nVM, TOPIA, nTOPIA, wo, nW1, wOff,
                                            X, BIG, L, U);
    // LN1 in place
    ln_kernel<<<Mrows, 256, 0, stream>>>(X, BIG, nullptr, n1_g + i * 512, n1_b + i * 512,
                                         X, BIG);
    // FFN chunked (row-local)
    for (int r0 = 0; r0 < Mrows; r0 += 2048) {
      gemm_kernel<<<dim3(32, 8), 256, 0, stream>>>(
          X + (ll)r0 * 512, BIG - (ll)r0 * 512, 0, 2048, 512,
          ff1_w, nW1, wOff, 512, 1, ff1_b + i * 512, 512, SC1, CSZ, 512, 0, 0, 0);
      gelu_kernel<<<(int)((CSZ + 255) / 256), 256, 0, stream>>>(SC1, CSZ, CSZ);
      gemm_kernel<<<dim3(32, 8), 256, 0, stream>>>(
          SC1, CSZ, 0, 2048, 512, ff2_w, nW1, wOff, 512, 1,
          ff2_b + i * 512, 512, SC2, CSZ, 512, 0, 0, 0);
      ln_kernel<<<2048, 256, 0, stream>>>(X + (ll)r0 * 512, BIG - (ll)r0 * 512, SC2,
                                          n2_g + i * 512, n2_b + i * 512,
                                          X + (ll)r0 * 512, BIG - (ll)r0 * 512);
    }

    if (i < 3) {
      // distill per batch: conv (wrap) -> SC1, BN+ELU, maxpool -> X[b, :L/2] (compacting)
      int L2 = L / 2;
      for (int b = 0; b < 8; b++) {
        for (int tp = 0; tp < 3; tp++) {
          gemm_kernel<<<dim3(L / 64, 8), 256, 0, stream>>>(
              X, BIG, b * L, L, 512, dconv_w, nDconvW, (ll)i * 786432 + tp, 3, 1536,
              (tp == 0 ? dconv_b + i * 512 : (const float*)nullptr), 512,
              SC1, CSZ, 512, tp - 1, 2, (tp > 0) ? 1 : 0);
        }
        bnelu_kernel<<<(int)(((ll)L * 512 + 255) / 256), 256, 0, stream>>>(
            SC1, CSZ, bn_g + i * 512, bn_b + i * 512, bn_m + i * 512, bn_v + i * 512,
            (ll)L * 512);
        maxpool_kernel<<<(int)(((ll)L2 * 512 + 255) / 256), 256, 0, stream>>>(
            SC1, CSZ, X + (ll)b * L2 * 512, BIG - (ll)b * L2 * 512, L, L2, (ll)L2 * 512);
      }
    }
  }

  // memory = LN(x) at L=256 -> fp32 out+80 ; pred -> out[0:80]
  ln_kernel<<<8 * 256, 256, 0, stream>>>(X, BIG, nullptr, enc_g, enc_b, out + 80, nOut - 80);
  pred_kernel<<<40, 64, 0, stream>>>(dec_bv, head_w, head_b, out, nOut);
}

// Round 10
// 15833.524 us; speedup vs baseline: 1.4744x; 1.4744x over previous
//
#include <hip/hip_runtime.h>
#include <hip/hip_bf16.h>
#include <math.h>
#include <stdint.h>

typedef long long ll;

__device__ __forceinline__ ll clampi(ll i, ll n) { return i < 0 ? 0 : (i >= n ? n - 1 : i); }

// ---------------- threefry2x32 (20 rounds, JAX/Random123 exact) ----------------
__host__ __device__ inline uint32_t rotl32(uint32_t v, int d) { return (v << d) | (v >> (32 - d)); }

#define TF_R4(a, b, c, d)                              \
  x0 += x1; x1 = rotl32(x1, a); x1 ^= x0;              \
  x0 += x1; x1 = rotl32(x1, b); x1 ^= x0;              \
  x0 += x1; x1 = rotl32(x1, c); x1 ^= x0;              \
  x0 += x1; x1 = rotl32(x1, d); x1 ^= x0;

__host__ __device__ inline void threefry(uint32_t k0, uint32_t k1, uint32_t x0, uint32_t x1,
                                         uint32_t* o0, uint32_t* o1) {
  uint32_t ks2 = k0 ^ k1 ^ 0x1BD11BDAu;
  x0 += k0; x1 += k1;
  TF_R4(13, 15, 26, 6)
  x0 += k1; x1 += ks2 + 1u;
  TF_R4(17, 29, 16, 24)
  x0 += ks2; x1 += k0 + 2u;
  TF_R4(13, 15, 26, 6)
  x0 += k0; x1 += k1 + 3u;
  TF_R4(17, 29, 16, 24)
  x0 += k1; x1 += ks2 + 4u;
  TF_R4(13, 15, 26, 6)
  x0 += ks2; x1 += k0 + 5u;
  *o0 = x0; *o1 = x1;
}

// PE matching np make_pe fp32 pipeline
__device__ __forceinline__ float pe_val(int pos, int d) {
  int k2 = (d >> 1) << 1;
  float div = expf((float)k2 * (-9.210340371976184f / 512.0f));
  float arg = (float)pos * div;
  return (d & 1) ? cosf(arg) : sinf(arg);
}

// ---------------- kernels ----------------

// embed one batch b: out[l,d] = src[b,l,:6]@in_w[:,d] + in_b[d] + pe(l,d)
__global__ __launch_bounds__(256) void embed_b_kernel(const float* __restrict__ src,
                                                      const float* __restrict__ in_w,
                                                      const float* __restrict__ in_b,
                                                      int b, float* __restrict__ out) {
  ll i = (ll)blockIdx.x * 256 + threadIdx.x;
  if (i >= (ll)2048 * 512) return;
  int d = (int)(i & 511);
  int l = (int)(i >> 9);
  float acc = in_b[d];
#pragma unroll
  for (int j = 0; j < 6; j++)
    acc = fmaf(src[((ll)b * 2048 + l) * 6 + j], in_w[j * 512 + d], acc);
  acc += pe_val(l, d);
  out[i] = acc;
}

// Tiled GEMM, 64x64 tile, 256 threads, 4x4 acc, float4 staging + b128 LDS reads.
// C[m,n] = sum_{tp<taps} sum_k A[(b*L + l2(tp))*K + k] * W[wOffBase+tpoff + k*wSK + n*wSN] (+bias)
// taps=3 fuses 3 conv taps (shift=tp-1, W offset +tp). shiftMode: 0 none, 1 zero-pad, 2 wrap.
// fuse: 0 none, 1 gelu(exact erf).
__global__ __launch_bounds__(256) void gemm_kernel(
    const float* __restrict__ A, int mBase, int L, int K,
    const float* __restrict__ W, ll wOffBase, int wSK, int wSN,
    const float* __restrict__ bias, float* __restrict__ C, int N,
    int taps, int shiftMode, int fuse) {
  __shared__ float As[16][68];     // stride 68: rows 16B-aligned (68*4=272=17*16)
  __shared__ float Bs[16][64];
  const int tid = threadIdx.x;
  const int tx = tid & 15, ty = tid >> 4;
  const int m0 = blockIdx.x * 64, n0 = blockIdx.y * 64;
  const int rowA = tid >> 2;        // 0..63
  const int kA0 = (tid & 3) << 2;   // 0,4,8,12
  const int kB = tid >> 4;          // 0..15
  const int nB0 = (tid & 15) << 2;  // 0..60

  const int gRow = mBase + m0 + rowA;
  const int b = gRow / L, l = gRow - b * L;

  float acc[4][4] = {};

  for (int tp = 0; tp < taps; tp++) {
    int shift = (taps == 3) ? tp - 1 : 0;
    int l2 = l + shift;
    bool valid = true;
    if (shiftMode == 1) {
      valid = (l2 >= 0 && l2 < L);
      if (!valid) l2 = 0;
    } else if (shiftMode == 2) {
      l2 = l2 < 0 ? l2 + L : (l2 >= L ? l2 - L : l2);
    }
    const float* aRow = A + (ll)(b * L + l2) * K;
    const ll wOff = wOffBase + (taps == 3 ? tp : 0);

    for (int k0 = 0; k0 < K; k0 += 16) {
      float4 av = make_float4(0.f, 0.f, 0.f, 0.f);
      if (valid) av = *(const float4*)(aRow + k0 + kA0);
      As[kA0 + 0][rowA] = av.x;
      As[kA0 + 1][rowA] = av.y;
      As[kA0 + 2][rowA] = av.z;
      As[kA0 + 3][rowA] = av.w;
      const int kw = k0 + kB;
      if (wSN == 1) {
        *(float4*)&Bs[kB][nB0] = *(const float4*)(W + wOff + (ll)kw * wSK + (n0 + nB0));
      } else {
#pragma unroll
        for (int j = 0; j < 4; j++)
          Bs[kB][nB0 + j] = W[wOff + (ll)kw * wSK + (ll)(n0 + nB0 + j) * wSN];
      }
      __syncthreads();
#pragma unroll
      for (int kk = 0; kk < 16; kk++) {
        float4 a4 = *(const float4*)&As[kk][ty << 2];
        float4 w4 = *(const float4*)&Bs[kk][tx << 2];
        acc[0][0] = fmaf(a4.x, w4.x, acc[0][0]); acc[0][1] = fmaf(a4.x, w4.y, acc[0][1]);
        acc[0][2] = fmaf(a4.x, w4.z, acc[0][2]); acc[0][3] = fmaf(a4.x, w4.w, acc[0][3]);
        acc[1][0] = fmaf(a4.y, w4.x, acc[1][0]); acc[1][1] = fmaf(a4.y, w4.y, acc[1][1]);
        acc[1][2] = fmaf(a4.y, w4.z, acc[1][2]); acc[1][3] = fmaf(a4.y, w4.w, acc[1][3]);
        acc[2][0] = fmaf(a4.z, w4.x, acc[2][0]); acc[2][1] = fmaf(a4.z, w4.y, acc[2][1]);
        acc[2][2] = fmaf(a4.z, w4.z, acc[2][2]); acc[2][3] = fmaf(a4.z, w4.w, acc[2][3]);
        acc[3][0] = fmaf(a4.w, w4.x, acc[3][0]); acc[3][1] = fmaf(a4.w, w4.y, acc[3][1]);
        acc[3][2] = fmaf(a4.w, w4.z, acc[3][2]); acc[3][3] = fmaf(a4.w, w4.w, acc[3][3]);
      }
      __syncthreads();
    }
  }

  float4 bv = make_float4(0.f, 0.f, 0.f, 0.f);
  if (bias) bv = *(const float4*)(bias + n0 + (tx << 2));
#pragma unroll
  for (int i2 = 0; i2 < 4; i2++) {
    int m = m0 + (ty << 2) + i2;
    float4 v;
    v.x = acc[i2][0] + bv.x;
    v.y = acc[i2][1] + bv.y;
    v.z = acc[i2][2] + bv.z;
    v.w = acc[i2][3] + bv.w;
    if (fuse == 1) {
      v.x = 0.5f * v.x * (1.f + erff(v.x * 0.70710678118654752f));
      v.y = 0.5f * v.y * (1.f + erff(v.y * 0.70710678118654752f));
      v.z = 0.5f * v.z * (1.f + erff(v.z * 0.70710678118654752f));
      v.w = 0.5f * v.w * (1.f + erff(v.w * 0.70710678118654752f));
    }
    *(float4*)(C + (ll)m * N + n0 + (tx << 2)) = v;
  }
}

// JAX randint (pow2 span), PARTITIONABLE threefry mode:
//   bits[m] = o0(k2; 0, m) ^ o1(k2; 0, m); idx = bits & (L-1)
__global__ void idx_kernel(int* __restrict__ idx, ll nIdx, uint32_t k0, uint32_t k1, int n,
                           int mask) {
  int m = blockIdx.x * 256 + threadIdx.x;
  if (m < n) {
    uint32_t o0, o1;
    threefry(k0, k1, 0u, (uint32_t)m, &o0, &o1);
    idx[clampi(m, nIdx)] = (int)((o0 ^ o1) & (uint32_t)mask);
  }
}

// M[b,l] = max_u(q.k_samp) - sum_u(q.k_samp)/L for (8, L, 64) per-head tensors
__global__ __launch_bounds__(256) void m_kernel(const float* __restrict__ Q,
                                                const float* __restrict__ Kk,
                                                const int* __restrict__ idx,
                                                float* __restrict__ M, int L, int U) {
  int wid = (int)(((ll)blockIdx.x * 256 + threadIdx.x) >> 6);
  int lane = threadIdx.x & 63;
  if (wid >= 8 * L) return;
  int b = wid / L, l = wid - b * L;
  float qv = Q[((ll)(b * L + l)) * 64 + lane];
  float mx = -INFINITY, sm = 0.f;
  const int* ip = idx + (ll)l * U;
  for (int uu = 0; uu < U; uu++) {
    int kr = ip[uu] & (L - 1);       // in-range by construction; mask is free insurance
    float p = qv * Kk[((ll)(b * L + kr)) * 64 + lane];
#pragma unroll
    for (int d = 32; d > 0; d >>= 1) p += __shfl_xor(p, d);
    mx = fmaxf(mx, p);
    sm += p;
  }
  if (lane == 0) M[(ll)b * L + l] = mx - sm / (float)L;
}

// iterative top-u staged in LDS; ties -> smaller index (lax.top_k semantics)
__global__ __launch_bounds__(256) void topk_kernel(const float* __restrict__ M,
                                                   int* __restrict__ topi, int L, int u) {
  __shared__ float mv[2048];
  __shared__ float sv[256];
  __shared__ int si[256];
  int t = threadIdx.x;
  ll base = (ll)blockIdx.x * L;
  for (int l = t; l < L; l += 256) mv[l] = M[base + l];
  __syncthreads();
  for (int j = 0; j < u; j++) {
    float bv = -INFINITY; int bi = 0x7fffffff;
    for (int l = t; l < L; l += 256) {
      float v = mv[l];
      if (v > bv) { bv = v; bi = l; }
    }
    sv[t] = bv; si[t] = bi;
    __syncthreads();
    for (int s = 128; s > 0; s >>= 1) {
      if (t < s) {
        float v2 = sv[t + s]; int i2 = si[t + s];
        if (v2 > sv[t] || (v2 == sv[t] && i2 < si[t])) { sv[t] = v2; si[t] = i2; }
      }
      __syncthreads();
    }
    if (t == 0) {
      topi[(ll)blockIdx.x * u + j] = si[0];
      mv[si[0] & 2047] = -INFINITY;
    }
    __syncthreads();
  }
}

__global__ __launch_bounds__(64) void qgather_kernel(const float* __restrict__ Q,
                                                     const int* __restrict__ topi,
                                                     float* __restrict__ QR, int L, int u) {
  int g = blockIdx.x;
  int b = g / u;
  int row = topi[g] & (L - 1);
  QR[(ll)g * 64 + threadIdx.x] = Q[((ll)(b * L + row)) * 64 + threadIdx.x];
}

// vm[b*64+e] = mean_l V[b,l,e]
__global__ __launch_bounds__(256) void vmean_kernel(const float* __restrict__ V,
                                                    float* __restrict__ vm, int L) {
  int b = blockIdx.x;
  int e = threadIdx.x & 63, p = threadIdx.x >> 6;
  __shared__ float s[4][64];
  float acc = 0.f;
  for (int l = p; l < L; l += 4) acc += V[((ll)(b * L + l)) * 64 + e];
  s[p][e] = acc;
  __syncthreads();
  if (threadIdx.x < 64)
    vm[(ll)b * 64 + threadIdx.x] =
        (s[0][threadIdx.x] + s[1][threadIdx.x] + s[2][threadIdx.x] + s[3][threadIdx.x]) / (float)L;
}

// full attention for one selected query row; write compact upd row
__global__ __launch_bounds__(256) void attn_kernel(const float* __restrict__ QR,
                                                   const float* __restrict__ Kk,
                                                   const float* __restrict__ V,
                                                   const int* __restrict__ topi,
                                                   float* __restrict__ upd, int L, int u) {
  int b = blockIdx.x / u;
  __shared__ float qs[64];
  __shared__ float sc[2048];
  __shared__ float red[256];
  __shared__ float upds[4][64];
  int t = threadIdx.x;
  if (t < 64) qs[t] = QR[(ll)blockIdx.x * 64 + t];
  __syncthreads();
  float lmax = -INFINITY;
  for (int l = t; l < L; l += 256) {
    const float4* kr = (const float4*)(Kk + ((ll)(b * L + l)) * 64);
    float d = 0.f;
#pragma unroll
    for (int e = 0; e < 16; e++) {
      float4 k4 = kr[e];
      float4 q4 = *(const float4*)&qs[e << 2];
      d = fmaf(q4.x, k4.x, d);
      d = fmaf(q4.y, k4.y, d);
      d = fmaf(q4.z, k4.z, d);
      d = fmaf(q4.w, k4.w, d);
    }
    d *= 0.125f;
    sc[l] = d;
    lmax = fmaxf(lmax, d);
  }
  red[t] = lmax;
  __syncthreads();
  for (int s = 128; s > 0; s >>= 1) { if (t < s) red[t] = fmaxf(red[t], red[t + s]); __syncthreads(); }
  float mx = red[0];
  __syncthreads();
  float lsum = 0.f;
  for (int l = t; l < L; l += 256) { float e = expf(sc[l] - mx); sc[l] = e; lsum += e; }
  red[t] = lsum;
  __syncthreads();
  for (int s = 128; s > 0; s >>= 1) { if (t < s) red[t] += red[t + s]; __syncthreads(); }
  float inv = 1.f / red[0];
  int e = t & 63, p = t >> 6;
  float partial = 0.f;
  for (int l = p; l < L; l += 4)
    partial = fmaf(sc[l], V[((ll)(b * L + l)) * 64 + e], partial);
  upds[p][e] = partial;
  __syncthreads();
  if (t < 64) {
    float s = (upds[0][t] + upds[1][t] + upds[2][t] + upds[3][t]) * inv;
    upd[(ll)blockIdx.x * 64 + t] = s;
  }
}

// BR[b,t] = bo[t] + sum_{h,e} VM[(h*8+b)*64+e] * Wo[wOff + (h*64+e)*512 + t]
__global__ __launch_bounds__(512) void baserow_kernel(const float* __restrict__ VM,
                                                      const float* __restrict__ Wo, ll wOff,
                                                      const float* __restrict__ bo,
                                                      float* __restrict__ BR) {
  int b = blockIdx.x, t = threadIdx.x;
  float acc = bo[t];
  for (int h = 0; h < 8; h++)
#pragma unroll 4
    for (int e = 0; e < 64; e++)
      acc = fmaf(VM[(ll)(h * 8 + b) * 64 + e], Wo[wOff + (ll)(h * 64 + e) * 512 + t], acc);
  BR[(ll)b * 512 + t] = acc;
}

// X[i] += BR[b(i)*512 + d]
__global__ __launch_bounds__(256) void bcast_kernel(float* __restrict__ X,
                                                    const float* __restrict__ BR,
                                                    int L, ll n) {
  ll i = (ll)blockIdx.x * 256 + threadIdx.x;
  if (i >= n) return;
  int d = (int)(i & 511);
  int b = (int)((i >> 9) / L);
  X[i] += BR[(ll)b * 512 + d];
}

// X[b, topi] += (upd - vm) @ Wo_h ; atomicAdd (rows may repeat across heads)
__global__ __launch_bounds__(512) void corr_kernel(const float* __restrict__ UPD,
                                                   const float* __restrict__ VM,
                                                   const int* __restrict__ topi,
                                                   const float* __restrict__ Wo, ll wOff,
                                                   float* __restrict__ X, int L, int u) {
  int g = blockIdx.x;                 // h*8*u + b*u + j
  int h = g / (8 * u);
  int r = g - h * 8 * u;
  int b = r / u;
  int row = topi[g] & (L - 1);
  int t = threadIdx.x;
  float c = 0.f;
#pragma unroll 4
  for (int e = 0; e < 64; e++) {
    float dv = UPD[(ll)g * 64 + e] - VM[(ll)(h * 8 + b) * 64 + e];
    c = fmaf(dv, Wo[wOff + (ll)(h * 64 + e) * 512 + t], c);
  }
  atomicAdd(&X[((ll)b * L + row) * 512 + t], c);
}

// layernorm over 512 of (x [+res]); in-place safe per-row
__global__ __launch_bounds__(256) void ln_kernel(const float* __restrict__ x,
                                                 const float* __restrict__ res,
                                                 const float* __restrict__ g,
                                                 const float* __restrict__ be,
                                                 float* __restrict__ out) {
  ll base = (ll)blockIdx.x * 512;
  int t = threadIdx.x;
  float v0 = x[base + t], v1 = x[base + 256 + t];
  if (res) { v0 += res[base + t]; v1 += res[base + 256 + t]; }
  __shared__ float red[256];
  red[t] = v0 + v1;
  __syncthreads();
  for (int s = 128; s > 0; s >>= 1) { if (t < s) red[t] += red[t + s]; __syncthreads(); }
  float mu = red[0] * (1.f / 512.f);
  __syncthreads();
  float d0 = v0 - mu, d1 = v1 - mu;
  red[t] = d0 * d0 + d1 * d1;
  __syncthreads();
  for (int s = 128; s > 0; s >>= 1) { if (t < s) red[t] += red[t + s]; __syncthreads(); }
  float rstd = 1.f / sqrtf(red[0] * (1.f / 512.f) + 1e-5f);
  out[base + t] = d0 * rstd * g[t] + be[t];
  out[base + 256 + t] = d1 * rstd * g[t + 256] + be[t + 256];
}

__global__ __launch_bounds__(256) void bnelu_kernel(float* __restrict__ x,
                                                    const float* __restrict__ g,
                                                    const float* __restrict__ b,
                                                    const float* __restrict__ rm,
                                                    const float* __restrict__ rv, ll n) {
  ll i = (ll)blockIdx.x * 256 + threadIdx.x;
  if (i >= n) return;
  int c = (int)(i & 511);
  float y = (x[i] - rm[c]) / sqrtf(rv[c] + 1e-5f) * g[c] + b[c];
  x[i] = y > 0.f ? y : expm1f(y);
}

// maxpool over one batch: in y (L x 512), out (L2 x 512)
__global__ __launch_bounds__(256) void maxpool_kernel(const float* __restrict__ y,
                                                      float* __restrict__ outp,
                                                      int L, int L2, ll n) {
  ll i = (ll)blockIdx.x * 256 + threadIdx.x;
  if (i >= n) return;
  int c = (int)(i & 511);
  int l2 = (int)(i >> 9);
  int l0 = 2 * l2 - 1;
  float m = -INFINITY;
#pragma unroll
  for (int w = 0; w < 3; w++) {
    int l = l0 + w;
    if (l >= 0 && l < L) m = fmaxf(m, y[(ll)l * 512 + c]);
  }
  outp[i] = m;
}

// pred rows t=5..9: tgt = dec_b + pe(t) + pe(b); fp32 out
__global__ __launch_bounds__(64) void pred_kernel(const float* __restrict__ dec_b,
                                                  const float* __restrict__ head_w,
                                                  const float* __restrict__ head_b,
                                                  float* __restrict__ out) {
  int b = blockIdx.x / 5, tt = blockIdx.x % 5, t = 5 + tt;
  int lane = threadIdx.x;
  float a0 = 0.f, a1 = 0.f;
  for (int d = lane; d < 512; d += 64) {
    float td = dec_b[d] + pe_val(t, d) + pe_val(b, d);
    a0 = fmaf(td, head_w[2 * d], a0);
    a1 = fmaf(td, head_w[2 * d + 1], a1);
  }
#pragma unroll
  for (int s = 32; s > 0; s >>= 1) { a0 += __shfl_xor(a0, s); a1 += __shfl_xor(a1, s); }
  if (lane == 0) {
    out[(ll)b * 10 + tt * 2 + 0] = a0 + head_b[0];
    out[(ll)b * 10 + tt * 2 + 1] = a1 + head_b[1];
  }
}

// ---------------- host ----------------
extern "C" void kernel_launch(void* const* d_in, const int* in_sizes, int n_in,
                              void* d_out, int out_size, void* d_ws, size_t ws_size,
                              hipStream_t stream) {
  if (n_in < 34) return;
  if (in_sizes[0] != 8 * 2048 * 6) return;
  if (in_sizes[4] != 512 * 512 * 3) return;
  if (in_sizes[6] != 4 * 512 * 512) return;
  if (in_sizes[22] != 3 * 512 * 512 * 3) return;
  if (in_sizes[33] != 2) return;
  if (ws_size < 55700000) return;

  const ll BIG = (ll)8 * 2048 * 512;
  const ll HSZ = (ll)8 * 2048 * 64;
  const ll CSZ = (ll)2048 * 512;

  const float* src    = (const float*)d_in[0];
  const float* in_w   = (const float*)d_in[2];
  const float* in_b   = (const float*)d_in[3];
  const float* conv_w = (const float*)d_in[4];
  const float* conv_b = (const float*)d_in[5];
  const float* wq = (const float*)d_in[6];
  const float* bq = (const float*)d_in[7];
  const float* wk = (const float*)d_in[8];
  const float* bk = (const float*)d_in[9];
  const float* wv = (const float*)d_in[10];
  const float* bv = (const float*)d_in[11];
  const float* wo = (const float*)d_in[12];
  const float* bo = (const float*)d_in[13];
  const float* n1_g = (const float*)d_in[14];
  const float* n1_b = (const float*)d_in[15];
  const float* ff1_w = (const float*)d_in[16];
  const float* ff1_b = (const float*)d_in[17];
  const float* ff2_w = (const float*)d_in[18];
  const float* ff2_b = (const float*)d_in[19];
  const float* n2_g = (const float*)d_in[20];
  const float* n2_b = (const float*)d_in[21];
  const float* dconv_w = (const float*)d_in[22];
  const float* dconv_b = (const float*)d_in[23];
  const float* bn_g = (const float*)d_in[24];
  const float* bn_b = (const float*)d_in[25];
  const float* bn_m = (const float*)d_in[26];
  const float* bn_v = (const float*)d_in[27];
  const float* enc_g = (const float*)d_in[28];
  const float* enc_b = (const float*)d_in[29];
  const float* dec_bv = (const float*)d_in[31];
  const float* head_w = (const float*)d_in[32];
  const float* head_b = (const float*)d_in[33];
  float* out = (float*)d_out;

  char* p = (char*)d_ws;
  float* X  = (float*)p; p += BIG * 4;
  float* QH = (float*)p; p += HSZ * 4;
  float* KH = (float*)p; p += HSZ * 4;
  float* VH = (float*)p; p += HSZ * 4;
  float* SC1 = (float*)p; p += CSZ * 4;
  float* SC2 = (float*)p; p += CSZ * 4;
  float* UPD = (float*)p; p += (ll)8 * 8 * 40 * 64 * 4;
  float* VM  = (float*)p; p += (ll)8 * 8 * 64 * 4;
  float* BR  = (float*)p; p += (ll)8 * 512 * 4;
  float* Mh  = (float*)p; p += (ll)8 * 2048 * 4;
  float* QR  = (float*)p; p += (ll)8 * 40 * 64 * 4;
  int* IDX   = (int*)p; p += (ll)2048 * 40 * 4;
  int* TOPIA = (int*)p;

  const ll nIDX = (ll)2048 * 40;

  // PRNG (JAX partitionable threefry): key_i = threefry((0,42),(0,i));
  // k2 = threefry(key_i,(0,1)); bits[m] = o0(k2;0,m)^o1(k2;0,m)
  uint32_t keys[4][2];
  for (int i = 0; i < 4; i++) {
    uint32_t K0, K1, g0, g1;
    threefry(0u, 42u, 0u, (uint32_t)i, &K0, &K1);
    threefry(K0, K1, 0u, 1u, &g0, &g1);
    keys[i][0] = g0;
    keys[i][1] = g1;
  }

  // embed + input conv (zero-pad, 3 taps fused), per batch through SC1
  for (int b = 0; b < 8; b++) {
    embed_b_kernel<<<(int)((CSZ + 255) / 256), 256, 0, stream>>>(src, in_w, in_b, b, SC1);
    gemm_kernel<<<dim3(32, 8), 256, 0, stream>>>(
        SC1, 0, 2048, 512, conv_w, 0, 3, 1536, conv_b, X + (ll)b * CSZ, 512, 3, 1, 0);
  }

  const int Ls[4] = {2048, 1024, 512, 256};
  const int Us[4] = {40, 35, 35, 30};

  for (int i = 0; i < 4; i++) {
    int L = Ls[i], U = Us[i];
    int Mrows = 8 * L;
    ll nelem = (ll)Mrows * 512;
    int LU = L * U;
    ll wOff = (ll)i * 262144;

    idx_kernel<<<(LU + 255) / 256, 256, 0, stream>>>(IDX, nIDX, keys[i][0], keys[i][1],
                                                     LU, L - 1);

    for (int h = 0; h < 8; h++) {
      gemm_kernel<<<dim3(Mrows / 64, 1), 256, 0, stream>>>(
          X, 0, L, 512, wq, wOff + h * 64, 512, 1, bq + i * 512 + h * 64, QH, 64, 1, 0, 0);
      gemm_kernel<<<dim3(Mrows / 64, 1), 256, 0, stream>>>(
          X, 0, L, 512, wk, wOff + h * 64, 512, 1, bk + i * 512 + h * 64, KH, 64, 1, 0, 0);
      gemm_kernel<<<dim3(Mrows / 64, 1), 256, 0, stream>>>(
          X, 0, L, 512, wv, wOff + h * 64, 512, 1, bv + i * 512 + h * 64, VH, 64, 1, 0, 0);

      m_kernel<<<(8 * L * 64) / 256, 256, 0, stream>>>(QH, KH, IDX, Mh, L, U);
      topk_kernel<<<8, 256, 0, stream>>>(Mh, TOPIA + (ll)h * 8 * U, L, U);
      qgather_kernel<<<8 * U, 64, 0, stream>>>(QH, TOPIA + (ll)h * 8 * U, QR, L, U);
      vmean_kernel<<<8, 256, 0, stream>>>(VH, VM + (ll)h * 8 * 64, L);
      attn_kernel<<<8 * U, 256, 0, stream>>>(QR, KH, VH, TOPIA + (ll)h * 8 * U,
                                             UPD + (ll)h * 8 * U * 64, L, U);
    }

    // a = ctx@Wo + bo folded into X: base rows + sparse corrections
    baserow_kernel<<<8, 512, 0, stream>>>(VM, wo, wOff, bo + i * 512, BR);
    bcast_kernel<<<(int)((nelem + 255) / 256), 256, 0, stream>>>(X, BR, L, nelem);
    corr_kernel<<<64 * U, 512, 0, stream>>>(UPD, VM, TOPIA, wo, wOff, X, L, U);
    ln_kernel<<<Mrows, 256, 0, stream>>>(X, nullptr, n1_g + i * 512, n1_b + i * 512, X);

    // FFN chunked: FF1+gelu fused -> SC1; FF2 -> SC2; LN2(X+SC2) -> X
    for (int r0 = 0; r0 < Mrows; r0 += 2048) {
      gemm_kernel<<<dim3(32, 8), 256, 0, stream>>>(
          X + (ll)r0 * 512, 0, 2048, 512, ff1_w, wOff, 512, 1, ff1_b + i * 512, SC1, 512,
          1, 0, 1);
      gemm_kernel<<<dim3(32, 8), 256, 0, stream>>>(
          SC1, 0, 2048, 512, ff2_w, wOff, 512, 1, ff2_b + i * 512, SC2, 512, 1, 0, 0);
      ln_kernel<<<2048, 256, 0, stream>>>(X + (ll)r0 * 512, SC2, n2_g + i * 512,
                                          n2_b + i * 512, X + (ll)r0 * 512);
    }

    if (i < 3) {
      int L2 = L / 2;
      for (int b = 0; b < 8; b++) {
        gemm_kernel<<<dim3(L / 64, 8), 256, 0, stream>>>(
            X, b * L, L, 512, dconv_w, (ll)i * 786432, 3, 1536, dconv_b + i * 512,
            SC1, 512, 3, 2, 0);
        bnelu_kernel<<<(int)(((ll)L * 512 + 255) / 256), 256, 0, stream>>>(
            SC1, bn_g + i * 512, bn_b + i * 512, bn_m + i * 512, bn_v + i * 512, (ll)L * 512);
        maxpool_kernel<<<(int)(((ll)L2 * 512 + 255) / 256), 256, 0, stream>>>(
            SC1, X + (ll)b * L2 * 512, L, L2, (ll)L2 * 512);
      }
    }
  }

  ln_kernel<<<8 * 256, 256, 0, stream>>>(X, nullptr, enc_g, enc_b, out + 80);
  pred_kernel<<<40, 64, 0, stream>>>(dec_bv, head_w, head_b, out);
}

// Round 11
// 12000.660 us; speedup vs baseline: 1.9453x; 1.3194x over previous
//
#include <hip/hip_runtime.h>
#include <hip/hip_bf16.h>
#include <math.h>
#include <stdint.h>

typedef long long ll;

// ---------------- threefry2x32 (20 rounds, JAX/Random123 exact) ----------------
__host__ __device__ inline uint32_t rotl32(uint32_t v, int d) { return (v << d) | (v >> (32 - d)); }

#define TF_R4(a, b, c, d)                              \
  x0 += x1; x1 = rotl32(x1, a); x1 ^= x0;              \
  x0 += x1; x1 = rotl32(x1, b); x1 ^= x0;              \
  x0 += x1; x1 = rotl32(x1, c); x1 ^= x0;              \
  x0 += x1; x1 = rotl32(x1, d); x1 ^= x0;

__host__ __device__ inline void threefry(uint32_t k0, uint32_t k1, uint32_t x0, uint32_t x1,
                                         uint32_t* o0, uint32_t* o1) {
  uint32_t ks2 = k0 ^ k1 ^ 0x1BD11BDAu;
  x0 += k0; x1 += k1;
  TF_R4(13, 15, 26, 6)
  x0 += k1; x1 += ks2 + 1u;
  TF_R4(17, 29, 16, 24)
  x0 += ks2; x1 += k0 + 2u;
  TF_R4(13, 15, 26, 6)
  x0 += k0; x1 += k1 + 3u;
  TF_R4(17, 29, 16, 24)
  x0 += k1; x1 += ks2 + 4u;
  TF_R4(13, 15, 26, 6)
  x0 += ks2; x1 += k0 + 5u;
  *o0 = x0; *o1 = x1;
}

__device__ __forceinline__ float pe_val(int pos, int d) {
  int k2 = (d >> 1) << 1;
  float div = expf((float)k2 * (-9.210340371976184f / 512.0f));
  float arg = (float)pos * div;
  return (d & 1) ? cosf(arg) : sinf(arg);
}

// ---------------- kernels ----------------

// embed nb batches starting at b0 into out (local rows)
__global__ __launch_bounds__(256) void embed_kernel(const float* __restrict__ src,
                                                    const float* __restrict__ in_w,
                                                    const float* __restrict__ in_b,
                                                    int b0, int nb, float* __restrict__ out) {
  ll i = (ll)blockIdx.x * 256 + threadIdx.x;
  if (i >= (ll)nb * 2048 * 512) return;
  int d = (int)(i & 511);
  ll r = i >> 9;
  int l = (int)(r & 2047);
  int b = b0 + (int)(r >> 11);
  float acc = in_b[d];
#pragma unroll
  for (int j = 0; j < 6; j++)
    acc = fmaf(src[((ll)b * 2048 + l) * 6 + j], in_w[j * 512 + d], acc);
  acc += pe_val(l, d);
  out[i] = acc;
}

// 128x64-tile GEMM, 256 threads, 8x4 acc. C local rows.
// fuse: 0 none, 1 gelu, 2 BN+ELU (bn_* indexed by column n).
__global__ __launch_bounds__(256) void gemm128_kernel(
    const float* __restrict__ A, int mBase, int L, int K,
    const float* __restrict__ W, ll wOffBase, int wSK, int wSN,
    const float* __restrict__ bias, float* __restrict__ C, int N,
    int taps, int shiftMode, int fuse,
    const float* __restrict__ bn_g, const float* __restrict__ bn_b,
    const float* __restrict__ bn_m, const float* __restrict__ bn_v) {
  __shared__ float As[16][128];
  __shared__ float Bs[16][64];
  const int tid = threadIdx.x;
  const int tx = tid & 15, ty = tid >> 4;
  const int m0 = blockIdx.x * 128, n0 = blockIdx.y * 64;
  const int rA = tid >> 2;
  const int kq = (tid & 3) << 2;
  const int kB = tid >> 4, nB0 = (tid & 15) << 2;

  float acc[8][4] = {};

  for (int tp = 0; tp < taps; tp++) {
    int shift = (taps == 3) ? tp - 1 : 0;
    const float* aR[2];
    bool val[2];
#pragma unroll
    for (int r = 0; r < 2; r++) {
      int gRow = mBase + m0 + rA + r * 64;
      int b = gRow / L, l = gRow - b * L;
      int l2 = l + shift;
      bool v = true;
      if (shiftMode == 1) { v = (l2 >= 0 && l2 < L); if (!v) l2 = 0; }
      else if (shiftMode == 2) { l2 = l2 < 0 ? l2 + L : (l2 >= L ? l2 - L : l2); }
      aR[r] = A + (ll)(b * L + l2) * K;
      val[r] = v;
    }
    const ll wOff = wOffBase + (taps == 3 ? tp : 0);

    for (int k0 = 0; k0 < K; k0 += 16) {
#pragma unroll
      for (int r = 0; r < 2; r++) {
        float4 av = make_float4(0.f, 0.f, 0.f, 0.f);
        if (val[r]) av = *(const float4*)(aR[r] + k0 + kq);
        As[kq + 0][rA + r * 64] = av.x;
        As[kq + 1][rA + r * 64] = av.y;
        As[kq + 2][rA + r * 64] = av.z;
        As[kq + 3][rA + r * 64] = av.w;
      }
      const int kw = k0 + kB;
      if (wSN == 1) {
        *(float4*)&Bs[kB][nB0] = *(const float4*)(W + wOff + (ll)kw * wSK + (n0 + nB0));
      } else {
#pragma unroll
        for (int j = 0; j < 4; j++)
          Bs[kB][nB0 + j] = W[wOff + (ll)kw * wSK + (ll)(n0 + nB0 + j) * wSN];
      }
      __syncthreads();
#pragma unroll
      for (int kk = 0; kk < 16; kk++) {
        float4 a0 = *(const float4*)&As[kk][ty << 3];
        float4 a1 = *(const float4*)&As[kk][(ty << 3) + 4];
        float4 w4 = *(const float4*)&Bs[kk][tx << 2];
        acc[0][0] = fmaf(a0.x, w4.x, acc[0][0]); acc[0][1] = fmaf(a0.x, w4.y, acc[0][1]);
        acc[0][2] = fmaf(a0.x, w4.z, acc[0][2]); acc[0][3] = fmaf(a0.x, w4.w, acc[0][3]);
        acc[1][0] = fmaf(a0.y, w4.x, acc[1][0]); acc[1][1] = fmaf(a0.y, w4.y, acc[1][1]);
        acc[1][2] = fmaf(a0.y, w4.z, acc[1][2]); acc[1][3] = fmaf(a0.y, w4.w, acc[1][3]);
        acc[2][0] = fmaf(a0.z, w4.x, acc[2][0]); acc[2][1] = fmaf(a0.z, w4.y, acc[2][1]);
        acc[2][2] = fmaf(a0.z, w4.z, acc[2][2]); acc[2][3] = fmaf(a0.z, w4.w, acc[2][3]);
        acc[3][0] = fmaf(a0.w, w4.x, acc[3][0]); acc[3][1] = fmaf(a0.w, w4.y, acc[3][1]);
        acc[3][2] = fmaf(a0.w, w4.z, acc[3][2]); acc[3][3] = fmaf(a0.w, w4.w, acc[3][3]);
        acc[4][0] = fmaf(a1.x, w4.x, acc[4][0]); acc[4][1] = fmaf(a1.x, w4.y, acc[4][1]);
        acc[4][2] = fmaf(a1.x, w4.z, acc[4][2]); acc[4][3] = fmaf(a1.x, w4.w, acc[4][3]);
        acc[5][0] = fmaf(a1.y, w4.x, acc[5][0]); acc[5][1] = fmaf(a1.y, w4.y, acc[5][1]);
        acc[5][2] = fmaf(a1.y, w4.z, acc[5][2]); acc[5][3] = fmaf(a1.y, w4.w, acc[5][3]);
        acc[6][0] = fmaf(a1.z, w4.x, acc[6][0]); acc[6][1] = fmaf(a1.z, w4.y, acc[6][1]);
        acc[6][2] = fmaf(a1.z, w4.z, acc[6][2]); acc[6][3] = fmaf(a1.z, w4.w, acc[6][3]);
        acc[7][0] = fmaf(a1.w, w4.x, acc[7][0]); acc[7][1] = fmaf(a1.w, w4.y, acc[7][1]);
        acc[7][2] = fmaf(a1.w, w4.z, acc[7][2]); acc[7][3] = fmaf(a1.w, w4.w, acc[7][3]);
      }
      __syncthreads();
    }
  }

  float4 bv = make_float4(0.f, 0.f, 0.f, 0.f);
  if (bias) bv = *(const float4*)(bias + n0 + (tx << 2));
  float4 g4, b4, m4, v4;
  if (fuse == 2) {
    g4 = *(const float4*)(bn_g + n0 + (tx << 2));
    b4 = *(const float4*)(bn_b + n0 + (tx << 2));
    m4 = *(const float4*)(bn_m + n0 + (tx << 2));
    v4 = *(const float4*)(bn_v + n0 + (tx << 2));
    v4.x = 1.f / sqrtf(v4.x + 1e-5f); v4.y = 1.f / sqrtf(v4.y + 1e-5f);
    v4.z = 1.f / sqrtf(v4.z + 1e-5f); v4.w = 1.f / sqrtf(v4.w + 1e-5f);
  }
#pragma unroll
  for (int i2 = 0; i2 < 8; i2++) {
    int m = m0 + (ty << 3) + i2;
    float4 v;
    v.x = acc[i2][0] + bv.x; v.y = acc[i2][1] + bv.y;
    v.z = acc[i2][2] + bv.z; v.w = acc[i2][3] + bv.w;
    if (fuse == 1) {
      v.x = 0.5f * v.x * (1.f + erff(v.x * 0.70710678118654752f));
      v.y = 0.5f * v.y * (1.f + erff(v.y * 0.70710678118654752f));
      v.z = 0.5f * v.z * (1.f + erff(v.z * 0.70710678118654752f));
      v.w = 0.5f * v.w * (1.f + erff(v.w * 0.70710678118654752f));
    } else if (fuse == 2) {
      v.x = (v.x - m4.x) * v4.x * g4.x + b4.x; v.x = v.x > 0.f ? v.x : expm1f(v.x);
      v.y = (v.y - m4.y) * v4.y * g4.y + b4.y; v.y = v.y > 0.f ? v.y : expm1f(v.y);
      v.z = (v.z - m4.z) * v4.z * g4.z + b4.z; v.z = v.z > 0.f ? v.z : expm1f(v.z);
      v.w = (v.w - m4.w) * v4.w * g4.w + b4.w; v.w = v.w > 0.f ? v.w : expm1f(v.w);
    }
    *(float4*)(C + (ll)m * N + n0 + (tx << 2)) = v;
  }
}

// merged q/k/v projection for one head: grid (rows/64, 3); rows contiguous (8L x 512)
__global__ __launch_bounds__(256) void qkv_kernel(
    const float* __restrict__ X,
    const float* __restrict__ wq, const float* __restrict__ wk, const float* __restrict__ wv,
    ll wOff,
    const float* __restrict__ bq, const float* __restrict__ bk, const float* __restrict__ bv,
    float* __restrict__ QH, float* __restrict__ KH, float* __restrict__ VH) {
  const float* W; const float* bias; float* C;
  if (blockIdx.y == 0) { W = wq; bias = bq; C = QH; }
  else if (blockIdx.y == 1) { W = wk; bias = bk; C = KH; }
  else { W = wv; bias = bv; C = VH; }
  __shared__ float As[16][68];
  __shared__ float Bs[16][64];
  const int tid = threadIdx.x;
  const int tx = tid & 15, ty = tid >> 4;
  const int m0 = blockIdx.x * 64;
  const int rowA = tid >> 2;
  const int kA0 = (tid & 3) << 2;
  const int kB = tid >> 4, nB0 = (tid & 15) << 2;
  const float* aRow = X + (ll)(m0 + rowA) * 512;

  float acc[4][4] = {};
  for (int k0 = 0; k0 < 512; k0 += 16) {
    float4 av = *(const float4*)(aRow + k0 + kA0);
    As[kA0 + 0][rowA] = av.x;
    As[kA0 + 1][rowA] = av.y;
    As[kA0 + 2][rowA] = av.z;
    As[kA0 + 3][rowA] = av.w;
    *(float4*)&Bs[kB][nB0] = *(const float4*)(W + wOff + (ll)(k0 + kB) * 512 + nB0);
    __syncthreads();
#pragma unroll
    for (int kk = 0; kk < 16; kk++) {
      float4 a4 = *(const float4*)&As[kk][ty << 2];
      float4 w4 = *(const float4*)&Bs[kk][tx << 2];
      acc[0][0] = fmaf(a4.x, w4.x, acc[0][0]); acc[0][1] = fmaf(a4.x, w4.y, acc[0][1]);
      acc[0][2] = fmaf(a4.x, w4.z, acc[0][2]); acc[0][3] = fmaf(a4.x, w4.w, acc[0][3]);
      acc[1][0] = fmaf(a4.y, w4.x, acc[1][0]); acc[1][1] = fmaf(a4.y, w4.y, acc[1][1]);
      acc[1][2] = fmaf(a4.y, w4.z, acc[1][2]); acc[1][3] = fmaf(a4.y, w4.w, acc[1][3]);
      acc[2][0] = fmaf(a4.z, w4.x, acc[2][0]); acc[2][1] = fmaf(a4.z, w4.y, acc[2][1]);
      acc[2][2] = fmaf(a4.z, w4.z, acc[2][2]); acc[2][3] = fmaf(a4.z, w4.w, acc[2][3]);
      acc[3][0] = fmaf(a4.w, w4.x, acc[3][0]); acc[3][1] = fmaf(a4.w, w4.y, acc[3][1]);
      acc[3][2] = fmaf(a4.w, w4.z, acc[3][2]); acc[3][3] = fmaf(a4.w, w4.w, acc[3][3]);
    }
    __syncthreads();
  }
  float4 bv4 = *(const float4*)(bias + (tx << 2));
#pragma unroll
  for (int i2 = 0; i2 < 4; i2++) {
    int m = m0 + (ty << 2) + i2;
    float4 v;
    v.x = acc[i2][0] + bv4.x; v.y = acc[i2][1] + bv4.y;
    v.z = acc[i2][2] + bv4.z; v.w = acc[i2][3] + bv4.w;
    *(float4*)(C + (ll)m * 64 + (tx << 2)) = v;
  }
}

// JAX randint (pow2 span), partitionable mode: bits[m] = o0(k2;0,m)^o1(k2;0,m)
__global__ void idx_kernel(int* __restrict__ idx, uint32_t k0, uint32_t k1, int n, int mask) {
  int m = blockIdx.x * 256 + threadIdx.x;
  if (m < n) {
    uint32_t o0, o1;
    threefry(k0, k1, 0u, (uint32_t)m, &o0, &o1);
    idx[m] = (int)((o0 ^ o1) & (uint32_t)mask);
  }
}

// M[b,l] = max_u(q.k_samp) - sum_u(q.k_samp)/L
__global__ __launch_bounds__(256) void m_kernel(const float* __restrict__ Q,
                                                const float* __restrict__ Kk,
                                                const int* __restrict__ idx,
                                                float* __restrict__ M, int L, int U) {
  int wid = (int)(((ll)blockIdx.x * 256 + threadIdx.x) >> 6);
  int lane = threadIdx.x & 63;
  if (wid >= 8 * L) return;
  int b = wid / L, l = wid - b * L;
  float qv = Q[((ll)(b * L + l)) * 64 + lane];
  float mx = -INFINITY, sm = 0.f;
  const int* ip = idx + (ll)l * U;
  for (int uu = 0; uu < U; uu++) {
    int kr = ip[uu] & (L - 1);
    float p = qv * Kk[((ll)(b * L + kr)) * 64 + lane];
#pragma unroll
    for (int d = 32; d > 0; d >>= 1) p += __shfl_xor(p, d);
    mx = fmaxf(mx, p);
    sm += p;
  }
  if (lane == 0) M[(ll)b * L + l] = mx - sm / (float)L;
}

// fused: topk (LDS) + qgather + vmean; one block per b
__global__ __launch_bounds__(256) void tgv_kernel(const float* __restrict__ M,
                                                  const float* __restrict__ Q,
                                                  const float* __restrict__ V,
                                                  int* __restrict__ topi,
                                                  float* __restrict__ QR,
                                                  float* __restrict__ vm, int L, int u) {
  __shared__ float mv[2048];
  __shared__ float sv[256];
  __shared__ int si[256];
  __shared__ int rows[40];
  __shared__ float s4[4][64];
  int b = blockIdx.x, t = threadIdx.x;
  ll base = (ll)b * L;
  for (int l = t; l < L; l += 256) mv[l] = M[base + l];
  __syncthreads();
  for (int j = 0; j < u; j++) {
    float bv = -INFINITY; int bi = 0x7fffffff;
    for (int l = t; l < L; l += 256) {
      float v = mv[l];
      if (v > bv) { bv = v; bi = l; }
    }
    sv[t] = bv; si[t] = bi;
    __syncthreads();
    for (int s = 128; s > 0; s >>= 1) {
      if (t < s) {
        float v2 = sv[t + s]; int i2 = si[t + s];
        if (v2 > sv[t] || (v2 == sv[t] && i2 < si[t])) { sv[t] = v2; si[t] = i2; }
      }
      __syncthreads();
    }
    if (t == 0) {
      topi[(ll)b * u + j] = si[0];
      rows[j] = si[0];
      mv[si[0] & 2047] = -INFINITY;
    }
    __syncthreads();
  }
  // qgather
  for (int idx = t; idx < u * 64; idx += 256) {
    int j = idx >> 6, e = idx & 63;
    int row = rows[j];
    QR[((ll)b * u + j) * 64 + e] = Q[((ll)(b * L + row)) * 64 + e];
  }
  // vmean
  int e = t & 63, p = t >> 6;
  float acc = 0.f;
  for (int l = p; l < L; l += 4) acc += V[((ll)(b * L + l)) * 64 + e];
  s4[p][e] = acc;
  __syncthreads();
  if (t < 64)
    vm[(ll)b * 64 + t] = (s4[0][t] + s4[1][t] + s4[2][t] + s4[3][t]) / (float)L;
}

// full attention for one selected query row; write compact upd row
__global__ __launch_bounds__(256) void attn_kernel(const float* __restrict__ QR,
                                                   const float* __restrict__ Kk,
                                                   const float* __restrict__ V,
                                                   float* __restrict__ upd, int L, int u) {
  int b = blockIdx.x / u;
  __shared__ float qs[64];
  __shared__ float sc[2048];
  __shared__ float red[256];
  __shared__ float upds[4][64];
  int t = threadIdx.x;
  if (t < 64) qs[t] = QR[(ll)blockIdx.x * 64 + t];
  __syncthreads();
  float lmax = -INFINITY;
  for (int l = t; l < L; l += 256) {
    const float4* kr = (const float4*)(Kk + ((ll)(b * L + l)) * 64);
    float d = 0.f;
#pragma unroll
    for (int e = 0; e < 16; e++) {
      float4 k4 = kr[e];
      float4 q4 = *(const float4*)&qs[e << 2];
      d = fmaf(q4.x, k4.x, d);
      d = fmaf(q4.y, k4.y, d);
      d = fmaf(q4.z, k4.z, d);
      d = fmaf(q4.w, k4.w, d);
    }
    d *= 0.125f;
    sc[l] = d;
    lmax = fmaxf(lmax, d);
  }
  red[t] = lmax;
  __syncthreads();
  for (int s = 128; s > 0; s >>= 1) { if (t < s) red[t] = fmaxf(red[t], red[t + s]); __syncthreads(); }
  float mx = red[0];
  __syncthreads();
  float lsum = 0.f;
  for (int l = t; l < L; l += 256) { float e = expf(sc[l] - mx); sc[l] = e; lsum += e; }
  red[t] = lsum;
  __syncthreads();
  for (int s = 128; s > 0; s >>= 1) { if (t < s) red[t] += red[t + s]; __syncthreads(); }
  float inv = 1.f / red[0];
  int e = t & 63, p = t >> 6;
  float partial = 0.f;
  for (int l = p; l < L; l += 4)
    partial = fmaf(sc[l], V[((ll)(b * L + l)) * 64 + e], partial);
  upds[p][e] = partial;
  __syncthreads();
  if (t < 64) {
    float s = (upds[0][t] + upds[1][t] + upds[2][t] + upds[3][t]) * inv;
    upd[(ll)blockIdx.x * 64 + t] = s;
  }
}

// BR[b,t] = bo[t] + sum_{h,e} VM[(h*8+b)*64+e] * Wo[wOff + (h*64+e)*512 + t]
__global__ __launch_bounds__(512) void baserow_kernel(const float* __restrict__ VM,
                                                      const float* __restrict__ Wo, ll wOff,
                                                      const float* __restrict__ bo,
                                                      float* __restrict__ BR) {
  int b = blockIdx.x, t = threadIdx.x;
  float acc = bo[t];
  for (int h = 0; h < 8; h++)
#pragma unroll 4
    for (int e = 0; e < 64; e++)
      acc = fmaf(VM[(ll)(h * 8 + b) * 64 + e], Wo[wOff + (ll)(h * 64 + e) * 512 + t], acc);
  BR[(ll)b * 512 + t] = acc;
}

__global__ __launch_bounds__(256) void bcast_kernel(float* __restrict__ X,
                                                    const float* __restrict__ BR,
                                                    int L, ll n) {
  ll i = (ll)blockIdx.x * 256 + threadIdx.x;
  if (i >= n) return;
  int d = (int)(i & 511);
  int b = (int)((i >> 9) / L);
  X[i] += BR[(ll)b * 512 + d];
}

// X[b, topi] += (upd - vm) @ Wo_h ; atomicAdd (rows may repeat across heads)
__global__ __launch_bounds__(512) void corr_kernel(const float* __restrict__ UPD,
                                                   const float* __restrict__ VM,
                                                   const int* __restrict__ topi,
                                                   const float* __restrict__ Wo, ll wOff,
                                                   float* __restrict__ X, int L, int u) {
  int g = blockIdx.x;
  int h = g / (8 * u);
  int r = g - h * 8 * u;
  int b = r / u;
  int row = topi[g] & (L - 1);
  int t = threadIdx.x;
  float c = 0.f;
#pragma unroll 4
  for (int e = 0; e < 64; e++) {
    float dv = UPD[(ll)g * 64 + e] - VM[(ll)(h * 8 + b) * 64 + e];
    c = fmaf(dv, Wo[wOff + (ll)(h * 64 + e) * 512 + t], c);
  }
  atomicAdd(&X[((ll)b * L + row) * 512 + t], c);
}

// layernorm over 512 of (x [+res])
__global__ __launch_bounds__(256) void ln_kernel(const float* __restrict__ x,
                                                 const float* __restrict__ res,
                                                 const float* __restrict__ g,
                                                 const float* __restrict__ be,
                                                 float* __restrict__ out) {
  ll base = (ll)blockIdx.x * 512;
  int t = threadIdx.x;
  float v0 = x[base + t], v1 = x[base + 256 + t];
  if (res) { v0 += res[base + t]; v1 += res[base + 256 + t]; }
  __shared__ float red[256];
  red[t] = v0 + v1;
  __syncthreads();
  for (int s = 128; s > 0; s >>= 1) { if (t < s) red[t] += red[t + s]; __syncthreads(); }
  float mu = red[0] * (1.f / 512.f);
  __syncthreads();
  float d0 = v0 - mu, d1 = v1 - mu;
  red[t] = d0 * d0 + d1 * d1;
  __syncthreads();
  for (int s = 128; s > 0; s >>= 1) { if (t < s) red[t] += red[t + s]; __syncthreads(); }
  float rstd = 1.f / sqrtf(red[0] * (1.f / 512.f) + 1e-5f);
  out[base + t] = d0 * rstd * g[t] + be[t];
  out[base + 256 + t] = d1 * rstd * g[t + 256] + be[t + 256];
}

// maxpool over nb local batches: y (nb x L x 512) -> outp (nb x L2 x 512)
__global__ __launch_bounds__(256) void maxpool_kernel(const float* __restrict__ y,
                                                      float* __restrict__ outp,
                                                      int L, int L2, int nb) {
  ll n = (ll)nb * L2 * 512;
  ll i = (ll)blockIdx.x * 256 + threadIdx.x;
  if (i >= n) return;
  int per = L2 * 512;
  int bb = (int)(i / per);
  int rem = (int)(i - (ll)bb * per);
  int c = rem & 511;
  int l2 = rem >> 9;
  int l0 = 2 * l2 - 1;
  float m = -INFINITY;
#pragma unroll
  for (int w = 0; w < 3; w++) {
    int l = l0 + w;
    if (l >= 0 && l < L) m = fmaxf(m, y[((ll)bb * L + l) * 512 + c]);
  }
  outp[i] = m;
}

// pred rows t=5..9
__global__ __launch_bounds__(64) void pred_kernel(const float* __restrict__ dec_b,
                                                  const float* __restrict__ head_w,
                                                  const float* __restrict__ head_b,
                                                  float* __restrict__ out) {
  int b = blockIdx.x / 5, tt = blockIdx.x % 5, t = 5 + tt;
  int lane = threadIdx.x;
  float a0 = 0.f, a1 = 0.f;
  for (int d = lane; d < 512; d += 64) {
    float td = dec_b[d] + pe_val(t, d) + pe_val(b, d);
    a0 = fmaf(td, head_w[2 * d], a0);
    a1 = fmaf(td, head_w[2 * d + 1], a1);
  }
#pragma unroll
  for (int s = 32; s > 0; s >>= 1) { a0 += __shfl_xor(a0, s); a1 += __shfl_xor(a1, s); }
  if (lane == 0) {
    out[(ll)b * 10 + tt * 2 + 0] = a0 + head_b[0];
    out[(ll)b * 10 + tt * 2 + 1] = a1 + head_b[1];
  }
}

// ---------------- host ----------------
extern "C" void kernel_launch(void* const* d_in, const int* in_sizes, int n_in,
                              void* d_out, int out_size, void* d_ws, size_t ws_size,
                              hipStream_t stream) {
  if (n_in < 34) return;
  if (in_sizes[0] != 8 * 2048 * 6) return;
  if (in_sizes[4] != 512 * 512 * 3) return;
  if (in_sizes[6] != 4 * 512 * 512) return;
  if (in_sizes[22] != 3 * 512 * 512 * 3) return;
  if (in_sizes[33] != 2) return;
  if (ws_size < 55700000) return;

  const ll BIG = (ll)8 * 2048 * 512;
  const ll HSZ = (ll)8 * 2048 * 64;
  const ll CSZ = (ll)2048 * 512;

  const float* src    = (const float*)d_in[0];
  const float* in_w   = (const float*)d_in[2];
  const float* in_b   = (const float*)d_in[3];
  const float* conv_w = (const float*)d_in[4];
  const float* conv_b = (const float*)d_in[5];
  const float* wq = (const float*)d_in[6];
  const float* bq = (const float*)d_in[7];
  const float* wk = (const float*)d_in[8];
  const float* bk = (const float*)d_in[9];
  const float* wv = (const float*)d_in[10];
  const float* bv = (const float*)d_in[11];
  const float* wo = (const float*)d_in[12];
  const float* bo = (const float*)d_in[13];
  const float* n1_g = (const float*)d_in[14];
  const float* n1_b = (const float*)d_in[15];
  const float* ff1_w = (const float*)d_in[16];
  const float* ff1_b = (const float*)d_in[17];
  const float* ff2_w = (const float*)d_in[18];
  const float* ff2_b = (const float*)d_in[19];
  const float* n2_g = (const float*)d_in[20];
  const float* n2_b = (const float*)d_in[21];
  const float* dconv_w = (const float*)d_in[22];
  const float* dconv_b = (const float*)d_in[23];
  const float* bn_g = (const float*)d_in[24];
  const float* bn_b = (const float*)d_in[25];
  const float* bn_m = (const float*)d_in[26];
  const float* bn_v = (const float*)d_in[27];
  const float* enc_g = (const float*)d_in[28];
  const float* enc_b = (const float*)d_in[29];
  const float* dec_bv = (const float*)d_in[31];
  const float* head_w = (const float*)d_in[32];
  const float* head_b = (const float*)d_in[33];
  float* out = (float*)d_out;

  char* p = (char*)d_ws;
  float* X  = (float*)p; p += BIG * 4;
  float* QH = (float*)p; p += HSZ * 4;   // pool start
  float* KH = (float*)p; p += HSZ * 4;
  float* VH = (float*)p; p += HSZ * 4;
  float* SC1 = (float*)p; p += CSZ * 4;
  float* SC2 = (float*)p; p += CSZ * 4;
  float* UPD = (float*)p; p += (ll)8 * 8 * 40 * 64 * 4;
  float* VM  = (float*)p; p += (ll)8 * 8 * 64 * 4;
  float* BR  = (float*)p; p += (ll)8 * 512 * 4;
  float* Mh  = (float*)p; p += (ll)8 * 2048 * 4;
  float* QR  = (float*)p; p += (ll)8 * 40 * 64 * 4;
  int* IDX   = (int*)p; p += (ll)2048 * 40 * 4;
  int* TOPIA = (int*)p;
  (void)SC1; (void)SC2;

  // big scratch pool aliases (QH..SC2 = 5*CSZ floats; idle during embed/FFN/distill)
  float* P0 = QH;                       // 4096x512
  float* P1 = QH + (ll)4096 * 512;      // 4096x512

  uint32_t keys[4][2];
  for (int i = 0; i < 4; i++) {
    uint32_t K0, K1, g0, g1;
    threefry(0u, 42u, 0u, (uint32_t)i, &K0, &K1);
    threefry(K0, K1, 0u, 1u, &g0, &g1);
    keys[i][0] = g0;
    keys[i][1] = g1;
  }

  // embed + input conv (zero-pad, 3 taps fused), 2 batches per iter through P0
  for (int bp = 0; bp < 4; bp++) {
    embed_kernel<<<(int)((2 * CSZ + 255) / 256), 256, 0, stream>>>(src, in_w, in_b, bp * 2, 2, P0);
    gemm128_kernel<<<dim3(32, 8), 256, 0, stream>>>(
        P0, 0, 2048, 512, conv_w, 0, 3, 1536, conv_b, X + (ll)bp * 2 * CSZ, 512,
        3, 1, 0, nullptr, nullptr, nullptr, nullptr);
  }

  const int Ls[4] = {2048, 1024, 512, 256};
  const int Us[4] = {40, 35, 35, 30};

  for (int i = 0; i < 4; i++) {
    int L = Ls[i], U = Us[i];
    int Mrows = 8 * L;
    ll nelem = (ll)Mrows * 512;
    int LU = L * U;
    ll wOff = (ll)i * 262144;

    idx_kernel<<<(LU + 255) / 256, 256, 0, stream>>>(IDX, keys[i][0], keys[i][1], LU, L - 1);

    for (int h = 0; h < 8; h++) {
      qkv_kernel<<<dim3(Mrows / 64, 3), 256, 0, stream>>>(
          X, wq, wk, wv, wOff + h * 64,
          bq + i * 512 + h * 64, bk + i * 512 + h * 64, bv + i * 512 + h * 64, QH, KH, VH);
      m_kernel<<<(8 * L * 64) / 256, 256, 0, stream>>>(QH, KH, IDX, Mh, L, U);
      tgv_kernel<<<8, 256, 0, stream>>>(Mh, QH, VH, TOPIA + (ll)h * 8 * U, QR,
                                        VM + (ll)h * 8 * 64, L, U);
      attn_kernel<<<8 * U, 256, 0, stream>>>(QR, KH, VH, UPD + (ll)h * 8 * U * 64, L, U);
    }

    baserow_kernel<<<8, 512, 0, stream>>>(VM, wo, wOff, bo + i * 512, BR);
    bcast_kernel<<<(int)((nelem + 255) / 256), 256, 0, stream>>>(X, BR, L, nelem);
    corr_kernel<<<64 * U, 512, 0, stream>>>(UPD, VM, TOPIA, wo, wOff, X, L, U);
    ln_kernel<<<Mrows, 256, 0, stream>>>(X, nullptr, n1_g + i * 512, n1_b + i * 512, X);

    // FFN: FF1+gelu -> P0; FF2 -> P1; LN2(X+P1) -> X  (4096-row chunks)
    int CR = Mrows < 4096 ? Mrows : 4096;
    for (int r0 = 0; r0 < Mrows; r0 += CR) {
      gemm128_kernel<<<dim3(CR / 128, 8), 256, 0, stream>>>(
          X + (ll)r0 * 512, 0, CR, 512, ff1_w, wOff, 512, 1, ff1_b + i * 512, P0, 512,
          1, 0, 1, nullptr, nullptr, nullptr, nullptr);
      gemm128_kernel<<<dim3(CR / 128, 8), 256, 0, stream>>>(
          P0, 0, CR, 512, ff2_w, wOff, 512, 1, ff2_b + i * 512, P1, 512,
          1, 0, 0, nullptr, nullptr, nullptr, nullptr);
      ln_kernel<<<CR, 256, 0, stream>>>(X + (ll)r0 * 512, P1, n2_g + i * 512,
                                        n2_b + i * 512, X + (ll)r0 * 512);
    }

    if (i < 3) {
      // distill 2 batches per iter: conv(wrap,3 taps)+BN+ELU fused -> P0; maxpool -> X
      int L2 = L / 2;
      for (int bp = 0; bp < 4; bp++) {
        gemm128_kernel<<<dim3(2 * L / 128, 8), 256, 0, stream>>>(
            X, bp * 2 * L, L, 512, dconv_w, (ll)i * 786432, 3, 1536, dconv_b + i * 512,
            P0, 512, 3, 2, 2, bn_g + i * 512, bn_b + i * 512, bn_m + i * 512, bn_v + i * 512);
        maxpool_kernel<<<(int)(((ll)2 * L2 * 512 + 255) / 256), 256, 0, stream>>>(
            P0, X + (ll)bp * 2 * L2 * 512, L, L2, 2);
      }
    }
  }

  ln_kernel<<<8 * 256, 256, 0, stream>>>(X, nullptr, enc_g, enc_b, out + 80);
  pred_kernel<<<40, 64, 0, stream>>>(dec_bv, head_w, head_b, out);
}

// Round 12
// 11577.363 us; speedup vs baseline: 2.0164x; 1.0366x over previous
//
#include <hip/hip_runtime.h>
#include <hip/hip_bf16.h>
#include <math.h>
#include <stdint.h>

typedef long long ll;

// ---------------- threefry2x32 (20 rounds, JAX/Random123 exact) ----------------
__host__ __device__ inline uint32_t rotl32(uint32_t v, int d) { return (v << d) | (v >> (32 - d)); }

#define TF_R4(a, b, c, d)                              \
  x0 += x1; x1 = rotl32(x1, a); x1 ^= x0;              \
  x0 += x1; x1 = rotl32(x1, b); x1 ^= x0;              \
  x0 += x1; x1 = rotl32(x1, c); x1 ^= x0;              \
  x0 += x1; x1 = rotl32(x1, d); x1 ^= x0;

__host__ __device__ inline void threefry(uint32_t k0, uint32_t k1, uint32_t x0, uint32_t x1,
                                         uint32_t* o0, uint32_t* o1) {
  uint32_t ks2 = k0 ^ k1 ^ 0x1BD11BDAu;
  x0 += k0; x1 += k1;
  TF_R4(13, 15, 26, 6)
  x0 += k1; x1 += ks2 + 1u;
  TF_R4(17, 29, 16, 24)
  x0 += ks2; x1 += k0 + 2u;
  TF_R4(13, 15, 26, 6)
  x0 += k0; x1 += k1 + 3u;
  TF_R4(17, 29, 16, 24)
  x0 += k1; x1 += ks2 + 4u;
  TF_R4(13, 15, 26, 6)
  x0 += ks2; x1 += k0 + 5u;
  *o0 = x0; *o1 = x1;
}

__device__ __forceinline__ float pe_val(int pos, int d) {
  int k2 = (d >> 1) << 1;
  float div = expf((float)k2 * (-9.210340371976184f / 512.0f));
  float arg = (float)pos * div;
  return (d & 1) ? cosf(arg) : sinf(arg);
}

// ---------------- kernels ----------------

// embed nb batches starting at b0 into out (local rows)
__global__ __launch_bounds__(256) void embed_kernel(const float* __restrict__ src,
                                                    const float* __restrict__ in_w,
                                                    const float* __restrict__ in_b,
                                                    int b0, int nb, float* __restrict__ out) {
  ll i = (ll)blockIdx.x * 256 + threadIdx.x;
  if (i >= (ll)nb * 2048 * 512) return;
  int d = (int)(i & 511);
  ll r = i >> 9;
  int l = (int)(r & 2047);
  int b = b0 + (int)(r >> 11);
  float acc = in_b[d];
#pragma unroll
  for (int j = 0; j < 6; j++)
    acc = fmaf(src[((ll)b * 2048 + l) * 6 + j], in_w[j * 512 + d], acc);
  acc += pe_val(l, d);
  out[i] = acc;
}

// 32x64-tile GEMM, 256 threads, 2x4 acc. C local rows. Occupancy-oriented (small tile,
// 4x more blocks than 128-tile: grid (M/32, N/64)).
// fuse: 0 none, 1 gelu, 2 BN+ELU (bn_* indexed by column n).
__global__ __launch_bounds__(256) void gemm32_kernel(
    const float* __restrict__ A, int mBase, int L, int K,
    const float* __restrict__ W, ll wOffBase, int wSK, int wSN,
    const float* __restrict__ bias, float* __restrict__ C, int N,
    int taps, int shiftMode, int fuse,
    const float* __restrict__ bn_g, const float* __restrict__ bn_b,
    const float* __restrict__ bn_m, const float* __restrict__ bn_v) {
  __shared__ float As[16][33];
  __shared__ float Bs[16][64];
  const int tid = threadIdx.x;
  const int tx = tid & 15, ty = tid >> 4;     // tx: 4 cols, ty: 2 rows
  const int m0 = blockIdx.x * 32, n0 = blockIdx.y * 64;
  const int rA = tid >> 3;                    // 0..31 loader row
  const int kA = (tid & 7) << 1;              // 0,2,..,14
  const int kB = tid >> 4, nB0 = (tid & 15) << 2;

  float acc[2][4] = {};

  for (int tp = 0; tp < taps; tp++) {
    int shift = (taps == 3) ? tp - 1 : 0;
    int gRow = mBase + m0 + rA;
    int b = gRow / L, l = gRow - b * L;
    int l2 = l + shift;
    bool valid = true;
    if (shiftMode == 1) { valid = (l2 >= 0 && l2 < L); if (!valid) l2 = 0; }
    else if (shiftMode == 2) { l2 = l2 < 0 ? l2 + L : (l2 >= L ? l2 - L : l2); }
    const float* aRow = A + (ll)(b * L + l2) * K;
    const ll wOff = wOffBase + (taps == 3 ? tp : 0);

    for (int k0 = 0; k0 < K; k0 += 16) {
      float2 av = make_float2(0.f, 0.f);
      if (valid) av = *(const float2*)(aRow + k0 + kA);
      As[kA + 0][rA] = av.x;
      As[kA + 1][rA] = av.y;
      const int kw = k0 + kB;
      if (wSN == 1) {
        *(float4*)&Bs[kB][nB0] = *(const float4*)(W + wOff + (ll)kw * wSK + (n0 + nB0));
      } else {
#pragma unroll
        for (int j = 0; j < 4; j++)
          Bs[kB][nB0 + j] = W[wOff + (ll)kw * wSK + (ll)(n0 + nB0 + j) * wSN];
      }
      __syncthreads();
#pragma unroll
      for (int kk = 0; kk < 16; kk++) {
        float2 a2 = *(const float2*)&As[kk][ty << 1];
        float4 w4 = *(const float4*)&Bs[kk][tx << 2];
        acc[0][0] = fmaf(a2.x, w4.x, acc[0][0]); acc[0][1] = fmaf(a2.x, w4.y, acc[0][1]);
        acc[0][2] = fmaf(a2.x, w4.z, acc[0][2]); acc[0][3] = fmaf(a2.x, w4.w, acc[0][3]);
        acc[1][0] = fmaf(a2.y, w4.x, acc[1][0]); acc[1][1] = fmaf(a2.y, w4.y, acc[1][1]);
        acc[1][2] = fmaf(a2.y, w4.z, acc[1][2]); acc[1][3] = fmaf(a2.y, w4.w, acc[1][3]);
      }
      __syncthreads();
    }
  }

  float4 bv = make_float4(0.f, 0.f, 0.f, 0.f);
  if (bias) bv = *(const float4*)(bias + n0 + (tx << 2));
  float4 g4, b4, m4, v4;
  if (fuse == 2) {
    g4 = *(const float4*)(bn_g + n0 + (tx << 2));
    b4 = *(const float4*)(bn_b + n0 + (tx << 2));
    m4 = *(const float4*)(bn_m + n0 + (tx << 2));
    v4 = *(const float4*)(bn_v + n0 + (tx << 2));
    v4.x = 1.f / sqrtf(v4.x + 1e-5f); v4.y = 1.f / sqrtf(v4.y + 1e-5f);
    v4.z = 1.f / sqrtf(v4.z + 1e-5f); v4.w = 1.f / sqrtf(v4.w + 1e-5f);
  }
#pragma unroll
  for (int i2 = 0; i2 < 2; i2++) {
    int m = m0 + (ty << 1) + i2;
    float4 v;
    v.x = acc[i2][0] + bv.x; v.y = acc[i2][1] + bv.y;
    v.z = acc[i2][2] + bv.z; v.w = acc[i2][3] + bv.w;
    if (fuse == 1) {
      v.x = 0.5f * v.x * (1.f + erff(v.x * 0.70710678118654752f));
      v.y = 0.5f * v.y * (1.f + erff(v.y * 0.70710678118654752f));
      v.z = 0.5f * v.z * (1.f + erff(v.z * 0.70710678118654752f));
      v.w = 0.5f * v.w * (1.f + erff(v.w * 0.70710678118654752f));
    } else if (fuse == 2) {
      v.x = (v.x - m4.x) * v4.x * g4.x + b4.x; v.x = v.x > 0.f ? v.x : expm1f(v.x);
      v.y = (v.y - m4.y) * v4.y * g4.y + b4.y; v.y = v.y > 0.f ? v.y : expm1f(v.y);
      v.z = (v.z - m4.z) * v4.z * g4.z + b4.z; v.z = v.z > 0.f ? v.z : expm1f(v.z);
      v.w = (v.w - m4.w) * v4.w * g4.w + b4.w; v.w = v.w > 0.f ? v.w : expm1f(v.w);
    }
    *(float4*)(C + (ll)m * N + n0 + (tx << 2)) = v;
  }
}

// merged q/k/v projection for one head, 32x64 tile: grid (rows/32, 3)
__global__ __launch_bounds__(256) void qkv_kernel(
    const float* __restrict__ X,
    const float* __restrict__ wq, const float* __restrict__ wk, const float* __restrict__ wv,
    ll wOff,
    const float* __restrict__ bq, const float* __restrict__ bk, const float* __restrict__ bv,
    float* __restrict__ QH, float* __restrict__ KH, float* __restrict__ VH) {
  const float* W; const float* bias; float* C;
  if (blockIdx.y == 0) { W = wq; bias = bq; C = QH; }
  else if (blockIdx.y == 1) { W = wk; bias = bk; C = KH; }
  else { W = wv; bias = bv; C = VH; }
  __shared__ float As[16][33];
  __shared__ float Bs[16][64];
  const int tid = threadIdx.x;
  const int tx = tid & 15, ty = tid >> 4;
  const int m0 = blockIdx.x * 32;
  const int rA = tid >> 3;
  const int kA = (tid & 7) << 1;
  const int kB = tid >> 4, nB0 = (tid & 15) << 2;
  const float* aRow = X + (ll)(m0 + rA) * 512;

  float acc[2][4] = {};
  for (int k0 = 0; k0 < 512; k0 += 16) {
    float2 av = *(const float2*)(aRow + k0 + kA);
    As[kA + 0][rA] = av.x;
    As[kA + 1][rA] = av.y;
    *(float4*)&Bs[kB][nB0] = *(const float4*)(W + wOff + (ll)(k0 + kB) * 512 + nB0);
    __syncthreads();
#pragma unroll
    for (int kk = 0; kk < 16; kk++) {
      float2 a2 = *(const float2*)&As[kk][ty << 1];
      float4 w4 = *(const float4*)&Bs[kk][tx << 2];
      acc[0][0] = fmaf(a2.x, w4.x, acc[0][0]); acc[0][1] = fmaf(a2.x, w4.y, acc[0][1]);
      acc[0][2] = fmaf(a2.x, w4.z, acc[0][2]); acc[0][3] = fmaf(a2.x, w4.w, acc[0][3]);
      acc[1][0] = fmaf(a2.y, w4.x, acc[1][0]); acc[1][1] = fmaf(a2.y, w4.y, acc[1][1]);
      acc[1][2] = fmaf(a2.y, w4.z, acc[1][2]); acc[1][3] = fmaf(a2.y, w4.w, acc[1][3]);
    }
    __syncthreads();
  }
  float4 bv4 = *(const float4*)(bias + (tx << 2));
#pragma unroll
  for (int i2 = 0; i2 < 2; i2++) {
    int m = m0 + (ty << 1) + i2;
    float4 v;
    v.x = acc[i2][0] + bv4.x; v.y = acc[i2][1] + bv4.y;
    v.z = acc[i2][2] + bv4.z; v.w = acc[i2][3] + bv4.w;
    *(float4*)(C + (ll)m * 64 + (tx << 2)) = v;
  }
}

// JAX randint (pow2 span), partitionable mode: bits[m] = o0(k2;0,m)^o1(k2;0,m)
__global__ void idx_kernel(int* __restrict__ idx, uint32_t k0, uint32_t k1, int n, int mask) {
  int m = blockIdx.x * 256 + threadIdx.x;
  if (m < n) {
    uint32_t o0, o1;
    threefry(k0, k1, 0u, (uint32_t)m, &o0, &o1);
    idx[m] = (int)((o0 ^ o1) & (uint32_t)mask);
  }
}

// M[b,l] = max_u(q.k_samp) - sum_u(q.k_samp)/L
__global__ __launch_bounds__(256) void m_kernel(const float* __restrict__ Q,
                                                const float* __restrict__ Kk,
                                                const int* __restrict__ idx,
                                                float* __restrict__ M, int L, int U) {
  int wid = (int)(((ll)blockIdx.x * 256 + threadIdx.x) >> 6);
  int lane = threadIdx.x & 63;
  if (wid >= 8 * L) return;
  int b = wid / L, l = wid - b * L;
  float qv = Q[((ll)(b * L + l)) * 64 + lane];
  float mx = -INFINITY, sm = 0.f;
  const int* ip = idx + (ll)l * U;
  for (int uu = 0; uu < U; uu++) {
    int kr = ip[uu] & (L - 1);
    float p = qv * Kk[((ll)(b * L + kr)) * 64 + lane];
#pragma unroll
    for (int d = 32; d > 0; d >>= 1) p += __shfl_xor(p, d);
    mx = fmaxf(mx, p);
    sm += p;
  }
  if (lane == 0) M[(ll)b * L + l] = mx - sm / (float)L;
}

// fused: topk (LDS) + qgather + vmean; one block per b
__global__ __launch_bounds__(256) void tgv_kernel(const float* __restrict__ M,
                                                  const float* __restrict__ Q,
                                                  const float* __restrict__ V,
                                                  int* __restrict__ topi,
                                                  float* __restrict__ QR,
                                                  float* __restrict__ vm, int L, int u) {
  __shared__ float mv[2048];
  __shared__ float sv[256];
  __shared__ int si[256];
  __shared__ int rows[40];
  __shared__ float s4[4][64];
  int b = blockIdx.x, t = threadIdx.x;
  ll base = (ll)b * L;
  for (int l = t; l < L; l += 256) mv[l] = M[base + l];
  __syncthreads();
  for (int j = 0; j < u; j++) {
    float bv = -INFINITY; int bi = 0x7fffffff;
    for (int l = t; l < L; l += 256) {
      float v = mv[l];
      if (v > bv) { bv = v; bi = l; }
    }
    sv[t] = bv; si[t] = bi;
    __syncthreads();
    for (int s = 128; s > 0; s >>= 1) {
      if (t < s) {
        float v2 = sv[t + s]; int i2 = si[t + s];
        if (v2 > sv[t] || (v2 == sv[t] && i2 < si[t])) { sv[t] = v2; si[t] = i2; }
      }
      __syncthreads();
    }
    if (t == 0) {
      topi[(ll)b * u + j] = si[0];
      rows[j] = si[0];
      mv[si[0] & 2047] = -INFINITY;
    }
    __syncthreads();
  }
  for (int idx = t; idx < u * 64; idx += 256) {
    int j = idx >> 6, e = idx & 63;
    int row = rows[j];
    QR[((ll)b * u + j) * 64 + e] = Q[((ll)(b * L + row)) * 64 + e];
  }
  int e = t & 63, p2 = t >> 6;
  float acc = 0.f;
  for (int l = p2; l < L; l += 4) acc += V[((ll)(b * L + l)) * 64 + e];
  s4[p2][e] = acc;
  __syncthreads();
  if (t < 64)
    vm[(ll)b * 64 + t] = (s4[0][t] + s4[1][t] + s4[2][t] + s4[3][t]) / (float)L;
}

// full attention for one selected query row; write compact upd row
__global__ __launch_bounds__(256) void attn_kernel(const float* __restrict__ QR,
                                                   const float* __restrict__ Kk,
                                                   const float* __restrict__ V,
                                                   float* __restrict__ upd, int L, int u) {
  int b = blockIdx.x / u;
  __shared__ float qs[64];
  __shared__ float sc[2048];
  __shared__ float red[256];
  __shared__ float upds[4][64];
  int t = threadIdx.x;
  if (t < 64) qs[t] = QR[(ll)blockIdx.x * 64 + t];
  __syncthreads();
  float lmax = -INFINITY;
  for (int l = t; l < L; l += 256) {
    const float4* kr = (const float4*)(Kk + ((ll)(b * L + l)) * 64);
    float d = 0.f;
#pragma unroll
    for (int e = 0; e < 16; e++) {
      float4 k4 = kr[e];
      float4 q4 = *(const float4*)&qs[e << 2];
      d = fmaf(q4.x, k4.x, d);
      d = fmaf(q4.y, k4.y, d);
      d = fmaf(q4.z, k4.z, d);
      d = fmaf(q4.w, k4.w, d);
    }
    d *= 0.125f;
    sc[l] = d;
    lmax = fmaxf(lmax, d);
  }
  red[t] = lmax;
  __syncthreads();
  for (int s = 128; s > 0; s >>= 1) { if (t < s) red[t] = fmaxf(red[t], red[t + s]); __syncthreads(); }
  float mx = red[0];
  __syncthreads();
  float lsum = 0.f;
  for (int l = t; l < L; l += 256) { float e = expf(sc[l] - mx); sc[l] = e; lsum += e; }
  red[t] = lsum;
  __syncthreads();
  for (int s = 128; s > 0; s >>= 1) { if (t < s) red[t] += red[t + s]; __syncthreads(); }
  float inv = 1.f / red[0];
  int e = t & 63, p2 = t >> 6;
  float partial = 0.f;
  for (int l = p2; l < L; l += 4)
    partial = fmaf(sc[l], V[((ll)(b * L + l)) * 64 + e], partial);
  upds[p2][e] = partial;
  __syncthreads();
  if (t < 64) {
    float s = (upds[0][t] + upds[1][t] + upds[2][t] + upds[3][t]) * inv;
    upd[(ll)blockIdx.x * 64 + t] = s;
  }
}

// BR[b,t] = bo[t] + sum_{h,e} VM[(h*8+b)*64+e] * Wo[wOff + (h*64+e)*512 + t]
__global__ __launch_bounds__(512) void baserow_kernel(const float* __restrict__ VM,
                                                      const float* __restrict__ Wo, ll wOff,
                                                      const float* __restrict__ bo,
                                                      float* __restrict__ BR) {
  int b = blockIdx.x, t = threadIdx.x;
  float acc = bo[t];
  for (int h = 0; h < 8; h++)
#pragma unroll 4
    for (int e = 0; e < 64; e++)
      acc = fmaf(VM[(ll)(h * 8 + b) * 64 + e], Wo[wOff + (ll)(h * 64 + e) * 512 + t], acc);
  BR[(ll)b * 512 + t] = acc;
}

// X[b, topi] += (upd - vm) @ Wo_h ; atomicAdd (rows may repeat across heads)
__global__ __launch_bounds__(512) void corr_kernel(const float* __restrict__ UPD,
                                                   const float* __restrict__ VM,
                                                   const int* __restrict__ topi,
                                                   const float* __restrict__ Wo, ll wOff,
                                                   float* __restrict__ X, int L, int u) {
  int g = blockIdx.x;
  int h = g / (8 * u);
  int r = g - h * 8 * u;
  int b = r / u;
  int row = topi[g] & (L - 1);
  int t = threadIdx.x;
  float c = 0.f;
#pragma unroll 4
  for (int e = 0; e < 64; e++) {
    float dv = UPD[(ll)g * 64 + e] - VM[(ll)(h * 8 + b) * 64 + e];
    c = fmaf(dv, Wo[wOff + (ll)(h * 64 + e) * 512 + t], c);
  }
  atomicAdd(&X[((ll)b * L + row) * 512 + t], c);
}

// layernorm over 512 of (x [+res] [+br(b)]); br is per-batch row (B x 512), b = row/L
__global__ __launch_bounds__(256) void ln_kernel(const float* __restrict__ x,
                                                 const float* __restrict__ res,
                                                 const float* __restrict__ br, int L,
                                                 const float* __restrict__ g,
                                                 const float* __restrict__ be,
                                                 float* __restrict__ out) {
  ll base = (ll)blockIdx.x * 512;
  int t = threadIdx.x;
  float v0 = x[base + t], v1 = x[base + 256 + t];
  if (res) { v0 += res[base + t]; v1 += res[base + 256 + t]; }
  if (br) {
    int b = blockIdx.x / L;
    v0 += br[(ll)b * 512 + t];
    v1 += br[(ll)b * 512 + 256 + t];
  }
  __shared__ float red[256];
  red[t] = v0 + v1;
  __syncthreads();
  for (int s = 128; s > 0; s >>= 1) { if (t < s) red[t] += red[t + s]; __syncthreads(); }
  float mu = red[0] * (1.f / 512.f);
  __syncthreads();
  float d0 = v0 - mu, d1 = v1 - mu;
  red[t] = d0 * d0 + d1 * d1;
  __syncthreads();
  for (int s = 128; s > 0; s >>= 1) { if (t < s) red[t] += red[t + s]; __syncthreads(); }
  float rstd = 1.f / sqrtf(red[0] * (1.f / 512.f) + 1e-5f);
  out[base + t] = d0 * rstd * g[t] + be[t];
  out[base + 256 + t] = d1 * rstd * g[t + 256] + be[t + 256];
}

// maxpool over nb local batches
__global__ __launch_bounds__(256) void maxpool_kernel(const float* __restrict__ y,
                                                      float* __restrict__ outp,
                                                      int L, int L2, int nb) {
  ll n = (ll)nb * L2 * 512;
  ll i = (ll)blockIdx.x * 256 + threadIdx.x;
  if (i >= n) return;
  int per = L2 * 512;
  int bb = (int)(i / per);
  int rem = (int)(i - (ll)bb * per);
  int c = rem & 511;
  int l2 = rem >> 9;
  int l0 = 2 * l2 - 1;
  float m = -INFINITY;
#pragma unroll
  for (int w = 0; w < 3; w++) {
    int l = l0 + w;
    if (l >= 0 && l < L) m = fmaxf(m, y[((ll)bb * L + l) * 512 + c]);
  }
  outp[i] = m;
}

// pred rows t=5..9
__global__ __launch_bounds__(64) void pred_kernel(const float* __restrict__ dec_b,
                                                  const float* __restrict__ head_w,
                                                  const float* __restrict__ head_b,
                                                  float* __restrict__ out) {
  int b = blockIdx.x / 5, tt = blockIdx.x % 5, t = 5 + tt;
  int lane = threadIdx.x;
  float a0 = 0.f, a1 = 0.f;
  for (int d = lane; d < 512; d += 64) {
    float td = dec_b[d] + pe_val(t, d) + pe_val(b, d);
    a0 = fmaf(td, head_w[2 * d], a0);
    a1 = fmaf(td, head_w[2 * d + 1], a1);
  }
#pragma unroll
  for (int s = 32; s > 0; s >>= 1) { a0 += __shfl_xor(a0, s); a1 += __shfl_xor(a1, s); }
  if (lane == 0) {
    out[(ll)b * 10 + tt * 2 + 0] = a0 + head_b[0];
    out[(ll)b * 10 + tt * 2 + 1] = a1 + head_b[1];
  }
}

// ---------------- host ----------------
extern "C" void kernel_launch(void* const* d_in, const int* in_sizes, int n_in,
                              void* d_out, int out_size, void* d_ws, size_t ws_size,
                              hipStream_t stream) {
  if (n_in < 34) return;
  if (in_sizes[0] != 8 * 2048 * 6) return;
  if (in_sizes[4] != 512 * 512 * 3) return;
  if (in_sizes[6] != 4 * 512 * 512) return;
  if (in_sizes[22] != 3 * 512 * 512 * 3) return;
  if (in_sizes[33] != 2) return;
  if (ws_size < 55700000) return;

  const ll BIG = (ll)8 * 2048 * 512;
  const ll HSZ = (ll)8 * 2048 * 64;
  const ll CSZ = (ll)2048 * 512;

  const float* src    = (const float*)d_in[0];
  const float* in_w   = (const float*)d_in[2];
  const float* in_b   = (const float*)d_in[3];
  const float* conv_w = (const float*)d_in[4];
  const float* conv_b = (const float*)d_in[5];
  const float* wq = (const float*)d_in[6];
  const float* bq = (const float*)d_in[7];
  const float* wk = (const float*)d_in[8];
  const float* bk = (const float*)d_in[9];
  const float* wv = (const float*)d_in[10];
  const float* bv = (const float*)d_in[11];
  const float* wo = (const float*)d_in[12];
  const float* bo = (const float*)d_in[13];
  const float* n1_g = (const float*)d_in[14];
  const float* n1_b = (const float*)d_in[15];
  const float* ff1_w = (const float*)d_in[16];
  const float* ff1_b = (const float*)d_in[17];
  const float* ff2_w = (const float*)d_in[18];
  const float* ff2_b = (const float*)d_in[19];
  const float* n2_g = (const float*)d_in[20];
  const float* n2_b = (const float*)d_in[21];
  const float* dconv_w = (const float*)d_in[22];
  const float* dconv_b = (const float*)d_in[23];
  const float* bn_g = (const float*)d_in[24];
  const float* bn_b = (const float*)d_in[25];
  const float* bn_m = (const float*)d_in[26];
  const float* bn_v = (const float*)d_in[27];
  const float* enc_g = (const float*)d_in[28];
  const float* enc_b = (const float*)d_in[29];
  const float* dec_bv = (const float*)d_in[31];
  const float* head_w = (const float*)d_in[32];
  const float* head_b = (const float*)d_in[33];
  float* out = (float*)d_out;

  char* p = (char*)d_ws;
  float* X  = (float*)p; p += BIG * 4;
  float* QH = (float*)p; p += HSZ * 4;   // pool start
  float* KH = (float*)p; p += HSZ * 4;
  float* VH = (float*)p; p += HSZ * 4;
  float* SC1 = (float*)p; p += CSZ * 4;
  float* SC2 = (float*)p; p += CSZ * 4;
  float* UPD = (float*)p; p += (ll)8 * 8 * 40 * 64 * 4;
  float* VM  = (float*)p; p += (ll)8 * 8 * 64 * 4;
  float* BR  = (float*)p; p += (ll)8 * 512 * 4;
  float* Mh  = (float*)p; p += (ll)8 * 2048 * 4;
  float* QR  = (float*)p; p += (ll)8 * 40 * 64 * 4;
  int* IDX   = (int*)p; p += (ll)2048 * 40 * 4;
  int* TOPIA = (int*)p;
  (void)SC1; (void)SC2;

  float* P0 = QH;                       // 4096x512 alias
  float* P1 = QH + (ll)4096 * 512;      // 4096x512 alias

  uint32_t keys[4][2];
  for (int i = 0; i < 4; i++) {
    uint32_t K0, K1, g0, g1;
    threefry(0u, 42u, 0u, (uint32_t)i, &K0, &K1);
    threefry(K0, K1, 0u, 1u, &g0, &g1);
    keys[i][0] = g0;
    keys[i][1] = g1;
  }

  // embed + input conv (zero-pad, 3 taps fused), 2 batches per iter through P0
  for (int bp = 0; bp < 4; bp++) {
    embed_kernel<<<(int)((2 * CSZ + 255) / 256), 256, 0, stream>>>(src, in_w, in_b, bp * 2, 2, P0);
    gemm32_kernel<<<dim3(128, 8), 256, 0, stream>>>(
        P0, 0, 2048, 512, conv_w, 0, 3, 1536, conv_b, X + (ll)bp * 2 * CSZ, 512,
        3, 1, 0, nullptr, nullptr, nullptr, nullptr);
  }

  const int Ls[4] = {2048, 1024, 512, 256};
  const int Us[4] = {40, 35, 35, 30};

  for (int i = 0; i < 4; i++) {
    int L = Ls[i], U = Us[i];
    int Mrows = 8 * L;
    int LU = L * U;
    ll wOff = (ll)i * 262144;

    idx_kernel<<<(LU + 255) / 256, 256, 0, stream>>>(IDX, keys[i][0], keys[i][1], LU, L - 1);

    for (int h = 0; h < 8; h++) {
      qkv_kernel<<<dim3(Mrows / 32, 3), 256, 0, stream>>>(
          X, wq, wk, wv, wOff + h * 64,
          bq + i * 512 + h * 64, bk + i * 512 + h * 64, bv + i * 512 + h * 64, QH, KH, VH);
      m_kernel<<<(8 * L * 64) / 256, 256, 0, stream>>>(QH, KH, IDX, Mh, L, U);
      tgv_kernel<<<8, 256, 0, stream>>>(Mh, QH, VH, TOPIA + (ll)h * 8 * U, QR,
                                        VM + (ll)h * 8 * 64, L, U);
      attn_kernel<<<8 * U, 256, 0, stream>>>(QR, KH, VH, UPD + (ll)h * 8 * U * 64, L, U);
    }

    baserow_kernel<<<8, 512, 0, stream>>>(VM, wo, wOff, bo + i * 512, BR);
    corr_kernel<<<64 * U, 512, 0, stream>>>(UPD, VM, TOPIA, wo, wOff, X, L, U);
    // LN1 with BR folded in (X + corr + BR)
    ln_kernel<<<Mrows, 256, 0, stream>>>(X, nullptr, BR, L, n1_g + i * 512, n1_b + i * 512, X);

    // FFN: FF1+gelu -> P0; FF2 -> P1; LN2(X+P1) -> X  (4096-row chunks)
    int CR = Mrows < 4096 ? Mrows : 4096;
    for (int r0 = 0; r0 < Mrows; r0 += CR) {
      gemm32_kernel<<<dim3(CR / 32, 8), 256, 0, stream>>>(
          X + (ll)r0 * 512, 0, CR, 512, ff1_w, wOff, 512, 1, ff1_b + i * 512, P0, 512,
          1, 0, 1, nullptr, nullptr, nullptr, nullptr);
      gemm32_kernel<<<dim3(CR / 32, 8), 256, 0, stream>>>(
          P0, 0, CR, 512, ff2_w, wOff, 512, 1, ff2_b + i * 512, P1, 512,
          1, 0, 0, nullptr, nullptr, nullptr, nullptr);
      ln_kernel<<<CR, 256, 0, stream>>>(X + (ll)r0 * 512, P1, nullptr, L, n2_g + i * 512,
                                        n2_b + i * 512, X + (ll)r0 * 512);
    }

    if (i < 3) {
      // distill 2 batches per iter: conv(wrap,3 taps)+BN+ELU fused -> P0; maxpool -> X
      int L2 = L / 2;
      for (int bp = 0; bp < 4; bp++) {
        gemm32_kernel<<<dim3(2 * L / 32, 8), 256, 0, stream>>>(
            X, bp * 2 * L, L, 512, dconv_w, (ll)i * 786432, 3, 1536, dconv_b + i * 512,
            P0, 512, 3, 2, 2, bn_g + i * 512, bn_b + i * 512, bn_m + i * 512, bn_v + i * 512);
        maxpool_kernel<<<(int)(((ll)2 * L2 * 512 + 255) / 256), 256, 0, stream>>>(
            P0, X + (ll)bp * 2 * L2 * 512, L, L2, 2);
      }
    }
  }

  ln_kernel<<<8 * 256, 256, 0, stream>>>(X, nullptr, nullptr, 256, enc_g, enc_b, out + 80);
  pred_kernel<<<40, 64, 0, stream>>>(dec_bv, head_w, head_b, out);
}